// Round 2
// baseline (1074.505 us; speedup 1.0000x reference)
//
#include <hip/hip_runtime.h>
#include <math.h>

#define TT 406
#define DD 10
#define PP 128
#define FF 128
#define BB 64
#define NCPc 12
#define NCc 28

// ---------------- workspace layout (float offsets) ----------------
constexpr size_t OFF_GW    = 0;                       // 406
constexpr size_t OFF_M24   = 448;                     // 406*24 = 9744
constexpr size_t OFF_BY    = 10240;                   // 406
constexpr size_t OFF_MEAN1 = 10688;                   // 128
constexpr size_t OFF_RSTD1 = 10816;                   // 128
constexpr size_t OFF_MEAN2 = 10944;                   // 256
constexpr size_t OFF_RSTD2 = 11200;                   // 256
constexpr size_t OFF_MEAN3 = 11456;                   // 128
constexpr size_t OFF_RSTD3 = 11584;                   // 128
constexpr size_t OFF_GAP   = 11712;                   // 64*128 = 8192
constexpr size_t OFF_FEAT  = 19904;                   // 8192
constexpr size_t OFF_IDX   = 28096;                   // 64 (int)
constexpr size_t OFF_TMAP  = 28160;                   // 8192*24 = 196608
constexpr size_t OFF_OFFV  = 224768;                  // 64*1280 = 81920
constexpr size_t OFF_SCV   = 306688;                  // 81920
constexpr size_t OFF_H1    = 388608;                  // 64*128*406 = 3325952 (aliased as h3)
constexpr size_t OFF_H2    = OFF_H1 + (size_t)BB*128*TT; // 64*256*406 = 6651904
// total = 10,366,464 floats = 41.5 MB

// ---------------- TPS constant helpers ----------------
__device__ __forceinline__ double tcpx(int n){ return -1.0 + 2.0*(double)(n>>1)/13.0; }
__device__ __forceinline__ double tcpy(int n){ return (n&1) ? 1.0 : -1.0; }
__device__ __forceinline__ double Ufun(double d2){ return d2 > 0.0 ? 0.5*d2*log(d2) : 0.0; }

__global__ void k_tps_init(float* __restrict__ ws){
  __shared__ double aug[31][62];
  int tid = threadIdx.x; // 64 threads

  // gaussian weight table GW[delta] = exp(-delta^2/98)
  for (int i = tid; i < TT; i += 64){
    double d = (double)i;
    ws[OFF_GW + i] = (float)exp(-(d*d)/98.0);
  }

  // build [fk | I]
  for (int idx = tid; idx < 31*62; idx += 64){
    int r = idx/62, c = idx%62;
    double v = 0.0;
    if (c < 31){
      if (r < 28 && c < 28){
        double dx = tcpx(r)-tcpx(c), dy = tcpy(r)-tcpy(c);
        v = Ufun(dx*dx + dy*dy);
      } else if (r < 28 && c == 28) v = 1.0;
      else if (r == 28 && c < 28)  v = 1.0;
      else if (r < 28 && c == 29)  v = tcpx(r);
      else if (r < 28 && c == 30)  v = tcpy(r);
      else if (r == 29 && c < 28)  v = tcpx(c);
      else if (r == 30 && c < 28)  v = tcpy(c);
      else v = 0.0;
    } else {
      v = ((c-31) == r) ? 1.0 : 0.0;
    }
    aug[r][c] = v;
  }
  __syncthreads();

  // Gauss-Jordan with partial pivoting (double)
  for (int k = 0; k < 31; ++k){
    if (tid == 0){
      int piv = k; double best = fabs(aug[k][k]);
      for (int i = k+1; i < 31; ++i){
        double a = fabs(aug[i][k]);
        if (a > best){ best = a; piv = i; }
      }
      if (piv != k){
        for (int c = 0; c < 62; ++c){ double t = aug[k][c]; aug[k][c] = aug[piv][c]; aug[piv][c] = t; }
      }
      double pinv = 1.0/aug[k][k];
      for (int c = 0; c < 62; ++c) aug[k][c] *= pinv;
    }
    __syncthreads();
    for (int r = tid; r < 31; r += 64){
      if (r != k){
        double f = aug[r][k];
        if (f != 0.0){
          for (int c = 0; c < 62; ++c) aug[r][c] -= f*aug[k][c];
        }
      }
    }
    __syncthreads();
  }

  // M[t][m] = sum_n REP[t][n]*INV[n][m]; store cols 2..25 and base_y
  for (int t = tid; t < TT; t += 64){
    double yt = -1.0 + 2.0*(double)t/405.0;
    double rep[31];
    for (int n = 0; n < 28; ++n){
      double dx = -1.0 - tcpx(n), dy = yt - tcpy(n);
      rep[n] = Ufun(dx*dx + dy*dy);
    }
    rep[28] = 1.0; rep[29] = -1.0; rep[30] = yt;
    double Mm[28];
    for (int m = 0; m < 28; ++m){
      double s = 0.0;
      for (int n = 0; n < 31; ++n) s += rep[n]*aug[n][31+m];
      Mm[m] = s;
    }
    double base = 0.0;
    for (int m = 0; m < 28; ++m) base += Mm[m]*tcpy(m);
    ws[OFF_BY + t] = (float)base;
    for (int j = 0; j < 24; ++j) ws[OFF_M24 + (size_t)t*24 + j] = (float)Mm[j+2];
  }
}

// ---------------- encoder ----------------
__global__ void k_conv1(const float* __restrict__ x, const float* __restrict__ w,
                        const float* __restrict__ bias, float* __restrict__ h1){
  int t  = blockIdx.x*256 + threadIdx.x;
  int co = blockIdx.y, b = blockIdx.z;
  if (t >= TT) return;
  float acc = bias[co];
  const float* wr = w + co*80;           // (co,ci,k) -> co*80+ci*8+k
  const float* xb = x + (size_t)b*TT*DD; // (b,t,d)
  #pragma unroll
  for (int k = 0; k < 8; ++k){
    int tt = t + k - 3;
    if (tt >= 0 && tt < TT){
      const float* xr = xb + tt*DD;
      #pragma unroll
      for (int ci = 0; ci < DD; ++ci) acc += xr[ci]*wr[ci*8+k];
    }
  }
  h1[((size_t)b*128 + co)*TT + t] = acc;
}

template<int C>
__global__ void k_bnstats(const float* __restrict__ h, float* __restrict__ mean, float* __restrict__ rstd){
  int c = blockIdx.x, tid = threadIdx.x;
  double s1 = 0.0, s2 = 0.0;
  for (int n = tid; n < BB*TT; n += 256){
    int b = n/TT, t = n - b*TT;
    double v = (double)h[((size_t)b*C + c)*TT + t];
    s1 += v; s2 += v*v;
  }
  for (int o = 32; o > 0; o >>= 1){ s1 += __shfl_down(s1, o); s2 += __shfl_down(s2, o); }
  __shared__ double sh1[4], sh2[4];
  int wv = tid >> 6, ln = tid & 63;
  if (ln == 0){ sh1[wv] = s1; sh2[wv] = s2; }
  __syncthreads();
  if (tid == 0){
    double a = sh1[0]+sh1[1]+sh1[2]+sh1[3];
    double q = sh2[0]+sh2[1]+sh2[2]+sh2[3];
    double m = a/(double)(BB*TT);
    double v = q/(double)(BB*TT) - m*m;
    mean[c] = (float)m;
    rstd[c] = (float)(1.0/sqrt(v + 1e-5));
  }
}

__global__ __launch_bounds__(256) void k_conv2(const float* __restrict__ h1, const float* __restrict__ w,
    const float* __restrict__ bias, const float* __restrict__ g1, const float* __restrict__ b1,
    const float* __restrict__ mean1, const float* __restrict__ rstd1, float* __restrict__ h2){
  __shared__ float xs[128][20];
  int b = blockIdx.y, t0 = blockIdx.x*16, tid = threadIdx.x;
  for (int idx = tid; idx < 128*20; idx += 256){
    int ci = idx/20, tt = idx - ci*20;
    int t = t0 - 2 + tt;
    float v = 0.f;
    if (t >= 0 && t < TT){
      float raw = h1[((size_t)b*128 + ci)*TT + t];
      v = fmaxf(g1[ci]*(raw - mean1[ci])*rstd1[ci] + b1[ci], 0.f);
    }
    xs[ci][tt] = v;
  }
  __syncthreads();
  int co = tid; // 256 output channels
  float acc[16];
  float bz = bias[co];
  #pragma unroll
  for (int i = 0; i < 16; ++i) acc[i] = bz;
  const float* wr = w + (size_t)co*640; // (co,ci,k) -> co*640+ci*5+k
  for (int ci = 0; ci < 128; ++ci){
    float xr[20];
    #pragma unroll
    for (int i = 0; i < 20; ++i) xr[i] = xs[ci][i];
    #pragma unroll
    for (int k = 0; k < 5; ++k){
      float wv = wr[ci*5 + k];
      #pragma unroll
      for (int i = 0; i < 16; ++i) acc[i] += wv*xr[i+k];
    }
  }
  float* outp = h2 + ((size_t)b*256 + co)*TT;
  #pragma unroll
  for (int i = 0; i < 16; ++i){ int t = t0 + i; if (t < TT) outp[t] = acc[i]; }
}

__global__ __launch_bounds__(128) void k_conv3(const float* __restrict__ h2, const float* __restrict__ w,
    const float* __restrict__ bias, const float* __restrict__ g2, const float* __restrict__ b2,
    const float* __restrict__ mean2, const float* __restrict__ rstd2, float* __restrict__ h3){
  __shared__ float xs[256][18];
  int b = blockIdx.y, t0 = blockIdx.x*16, tid = threadIdx.x;
  for (int idx = tid; idx < 256*18; idx += 128){
    int ci = idx/18, tt = idx - ci*18;
    int t = t0 - 1 + tt;
    float v = 0.f;
    if (t >= 0 && t < TT){
      float raw = h2[((size_t)b*256 + ci)*TT + t];
      v = fmaxf(g2[ci]*(raw - mean2[ci])*rstd2[ci] + b2[ci], 0.f);
    }
    xs[ci][tt] = v;
  }
  __syncthreads();
  int co = tid; // 128
  float acc[16];
  float bz = bias[co];
  #pragma unroll
  for (int i = 0; i < 16; ++i) acc[i] = bz;
  const float* wr = w + (size_t)co*768; // co*768+ci*3+k
  for (int ci = 0; ci < 256; ++ci){
    float xr[18];
    #pragma unroll
    for (int i = 0; i < 18; ++i) xr[i] = xs[ci][i];
    #pragma unroll
    for (int k = 0; k < 3; ++k){
      float wv = wr[ci*3 + k];
      #pragma unroll
      for (int i = 0; i < 16; ++i) acc[i] += wv*xr[i+k];
    }
  }
  float* outp = h3 + ((size_t)b*128 + co)*TT;
  #pragma unroll
  for (int i = 0; i < 16; ++i){ int t = t0 + i; if (t < TT) outp[t] = acc[i]; }
}

__global__ void k_gap(const float* __restrict__ h3, const float* __restrict__ g3, const float* __restrict__ b3,
                      const float* __restrict__ mean3, const float* __restrict__ rstd3, float* __restrict__ gap){
  int c = blockIdx.x, b = blockIdx.y, tid = threadIdx.x; // 64
  const float* row = h3 + ((size_t)b*128 + c)*TT;
  float m = mean3[c], r = rstd3[c], g = g3[c], bb = b3[c];
  float s = 0.f;
  for (int t = tid; t < TT; t += 64) s += fmaxf(g*(row[t]-m)*r + bb, 0.f);
  for (int o = 32; o > 0; o >>= 1) s += __shfl_down(s, o);
  if (tid == 0) gap[b*128 + c] = s/406.f;
}

__global__ void k_feat(const float* __restrict__ gap, const float* __restrict__ fw,
                       const float* __restrict__ fb, float* __restrict__ feat){
  int id = blockIdx.x*256 + threadIdx.x;
  if (id >= BB*128) return;
  int b = id >> 7, f = id & 127;
  float acc = fb[f];
  const float* gr = gap + b*128;
  for (int c = 0; c < 128; ++c) acc += gr[c]*fw[c*128 + f];
  feat[id] = acc;
}

// ---------------- heads ----------------
__global__ void k_trans(const float* __restrict__ feat, const float* __restrict__ tw,
                        const float* __restrict__ tb, float* __restrict__ tmap2){
  int id = blockIdx.x*256 + threadIdx.x; // 64*12*256 = 196608
  int b = id/3072; int rem = id - b*3072; int k = rem >> 8; int o = rem & 255;
  float acc = tb[k*256 + o];
  const float* fr = feat + b*128;
  const float* wr = tw + ((size_t)k*128)*256 + o;
  for (int f = 0; f < 128; ++f) acc += fr[f]*wr[f*256];
  float val = tanhf(acc)*5.f;
  int p = o & 127, j = 2*k + (o >> 7);
  tmap2[((size_t)b*128 + p)*24 + j] = val;
}

__global__ void k_offscale(const float* __restrict__ feat, const float* __restrict__ ow,
                           const float* __restrict__ ob, const float* __restrict__ sw,
                           const float* __restrict__ sb, float* __restrict__ offv, float* __restrict__ scv){
  int id = blockIdx.x*256 + threadIdx.x; // 64*1280
  if (id >= BB*1280) return;
  int b = id/1280, o = id - b*1280;
  const float* fr = feat + b*128;
  float a1 = ob[o], a2 = sb[o];
  for (int f = 0; f < 128; ++f){
    float fv = fr[f];
    a1 += fv*ow[f*1280 + o];
    a2 += fv*sw[f*1280 + o];
  }
  offv[id] = tanhf(a1);
  scv[id]  = tanhf(a2)*0.75f + 1.25f;
}

// ---------------- smoothing ----------------
__global__ __launch_bounds__(448) void k_smooth(const float* __restrict__ x, const int* __restrict__ mask,
    const float* __restrict__ gwt, float* __restrict__ out_inps, float* __restrict__ out_ms){
  int b = blockIdx.x, tid = threadIdx.x;
  __shared__ float xs[TT*DD];
  __shared__ float ms[TT];
  __shared__ float gw[TT];
  for (int i = tid; i < TT*DD; i += 448) xs[i] = x[(size_t)b*TT*DD + i];
  for (int i = tid; i < TT; i += 448){ ms[i] = (float)mask[b*TT + i]; gw[i] = gwt[i]; }
  __syncthreads();
  int t = tid;
  if (t >= TT) return;
  float a[10];
  #pragma unroll
  for (int d = 0; d < 10; ++d) a[d] = 0.f;
  float msum = 0.f;
  for (int i = 0; i < TT; ++i){
    float w = gw[(t > i) ? (t - i) : (i - t)];
    msum += w*ms[i];
    #pragma unroll
    for (int d = 0; d < 10; ++d) a[d] += w*xs[i*10 + d];
  }
  out_ms[b*TT + t] = msum;
  float den = (msum == 0.f) ? 1.f : msum;
  #pragma unroll
  for (int d = 0; d < 10; ++d) out_inps[((size_t)b*TT + t)*10 + d] = a[d]/den;
}

// ---------------- distance / argmin / output ----------------
__global__ void k_dist(const float* __restrict__ wsf, const float* __restrict__ proto,
                       const float* __restrict__ inps, const float* __restrict__ msf,
                       const float* __restrict__ offv, const float* __restrict__ scv,
                       float* __restrict__ dist){
  int p = blockIdx.x, b = blockIdx.y, tid = threadIdx.x; // 64 threads
  const float* M24 = wsf + OFF_M24;
  const float* by  = wsf + OFF_BY;
  const float* tm  = wsf + OFF_TMAP + ((size_t)b*128 + p)*24;
  float tmr[24];
  #pragma unroll
  for (int j = 0; j < 24; ++j) tmr[j] = tm[j];
  float ofr[10], scr[10];
  #pragma unroll
  for (int d = 0; d < 10; ++d){
    ofr[d] = offv[((size_t)b*128 + p)*10 + d];
    scr[d] = scv [((size_t)b*128 + p)*10 + d];
  }
  float acc = 0.f;
  for (int t = tid; t < TT; t += 64){
    const float* Mr = M24 + (size_t)t*24;
    float y = by[t];
    #pragma unroll
    for (int j = 0; j < 24; ++j) y += Mr[j]*tmr[j];
    float pos = (y + 1.f)*0.5f*405.f;
    pos = fminf(fmaxf(pos, 0.f), 405.f);
    int i0 = (int)pos;
    float w = pos - (float)i0;
    int i1 = min(i0 + 1, 405);
    const float* p0 = proto + ((size_t)p*TT + i0)*10;
    const float* p1 = proto + ((size_t)p*TT + i1)*10;
    const float* xr = inps + ((size_t)b*TT + t)*10;
    float s = 0.f;
    #pragma unroll
    for (int d = 0; d < 10; ++d){
      float val = (p0[d]*(1.f - w) + p1[d]*w + ofr[d])*scr[d];
      float df = xr[d] - val;
      s += df*df;
    }
    acc += msf[b*TT + t]*s;
  }
  for (int o = 32; o > 0; o >>= 1) acc += __shfl_down(acc, o);
  if (tid == 0) dist[b*128 + p] = acc;
}

__global__ void k_argmin(const float* __restrict__ dist, const int* __restrict__ label,
                         int* __restrict__ idxws, float* __restrict__ out3, float* __restrict__ out4){
  int b = threadIdx.x;
  if (b >= BB) return;
  const float* dr = dist + b*128;
  float best = dr[0]; int bi = 0;
  for (int p = 1; p < 128; ++p){
    float v = dr[p];
    if (v < best){ best = v; bi = p; }
  }
  idxws[b] = bi;
  out3[b] = (float)bi;
  out4[b] = (float)label[b];
}

__global__ void k_out(const float* __restrict__ wsf, const float* __restrict__ proto,
                      const float* __restrict__ offv, const float* __restrict__ scv,
                      const int* __restrict__ idxws, float* __restrict__ out0){
  int b = blockIdx.y;
  int t = blockIdx.x*64 + threadIdx.x;
  if (t >= TT) return;
  int p = idxws[b];
  const float* tm = wsf + OFF_TMAP + ((size_t)b*128 + p)*24;
  const float* Mr = wsf + OFF_M24 + (size_t)t*24;
  float y = wsf[OFF_BY + t];
  #pragma unroll
  for (int j = 0; j < 24; ++j) y += Mr[j]*tm[j];
  float pos = (y + 1.f)*0.5f*405.f;
  pos = fminf(fmaxf(pos, 0.f), 405.f);
  int i0 = (int)pos;
  float w = pos - (float)i0;
  int i1 = min(i0 + 1, 405);
  const float* p0 = proto + ((size_t)p*TT + i0)*10;
  const float* p1 = proto + ((size_t)p*TT + i1)*10;
  #pragma unroll
  for (int d = 0; d < 10; ++d){
    float val = (p0[d]*(1.f - w) + p1[d]*w + offv[((size_t)b*128 + p)*10 + d])*scv[((size_t)b*128 + p)*10 + d];
    out0[((size_t)b*TT + t)*10 + d] = val;
  }
}

// ---------------- launch ----------------
extern "C" void kernel_launch(void* const* d_in, const int* in_sizes, int n_in,
                              void* d_out, int out_size, void* d_ws, size_t ws_size,
                              hipStream_t stream){
  const float* input_seq = (const float*)d_in[0];
  const int*   label     = (const int*)  d_in[1];
  const int*   mask      = (const int*)  d_in[2];
  const float* proto     = (const float*)d_in[3];
  const float* c1w = (const float*)d_in[4];  const float* c1b = (const float*)d_in[5];
  const float* g1  = (const float*)d_in[6];  const float* b1  = (const float*)d_in[7];
  const float* c2w = (const float*)d_in[8];  const float* c2b = (const float*)d_in[9];
  const float* g2  = (const float*)d_in[10]; const float* b2  = (const float*)d_in[11];
  const float* c3w = (const float*)d_in[12]; const float* c3b = (const float*)d_in[13];
  const float* g3  = (const float*)d_in[14]; const float* b3  = (const float*)d_in[15];
  const float* fw  = (const float*)d_in[16]; const float* fb  = (const float*)d_in[17];
  const float* tw  = (const float*)d_in[18]; const float* tb  = (const float*)d_in[19];
  const float* ow  = (const float*)d_in[20]; const float* ob  = (const float*)d_in[21];
  const float* sw  = (const float*)d_in[22]; const float* sb  = (const float*)d_in[23];

  float* wsf = (float*)d_ws;
  float* out0 = (float*)d_out;             // (B,T,D) 259840
  float* out1 = out0 + 259840;             // inp_s   259840
  float* out2 = out0 + 519680;             // dist    8192
  float* out3 = out0 + 527872;             // indices 64
  float* out4 = out0 + 527936;             // label   64
  float* out5 = out0 + 528000;             // mask_s  25984

  float* h1 = wsf + OFF_H1;
  float* h2 = wsf + OFF_H2;
  float* h3 = h1; // h1 dead after conv2

  k_tps_init<<<dim3(1), dim3(64), 0, stream>>>(wsf);
  k_conv1<<<dim3(2,128,BB), 256, 0, stream>>>(input_seq, c1w, c1b, h1);
  k_bnstats<128><<<128, 256, 0, stream>>>(h1, wsf+OFF_MEAN1, wsf+OFF_RSTD1);
  k_conv2<<<dim3(26,BB), 256, 0, stream>>>(h1, c2w, c2b, g1, b1, wsf+OFF_MEAN1, wsf+OFF_RSTD1, h2);
  k_bnstats<256><<<256, 256, 0, stream>>>(h2, wsf+OFF_MEAN2, wsf+OFF_RSTD2);
  k_conv3<<<dim3(26,BB), 128, 0, stream>>>(h2, c3w, c3b, g2, b2, wsf+OFF_MEAN2, wsf+OFF_RSTD2, h3);
  k_bnstats<128><<<128, 256, 0, stream>>>(h3, wsf+OFF_MEAN3, wsf+OFF_RSTD3);
  k_gap<<<dim3(128,BB), 64, 0, stream>>>(h3, g3, b3, wsf+OFF_MEAN3, wsf+OFF_RSTD3, wsf+OFF_GAP);
  k_feat<<<32, 256, 0, stream>>>(wsf+OFF_GAP, fw, fb, wsf+OFF_FEAT);
  k_trans<<<768, 256, 0, stream>>>(wsf+OFF_FEAT, tw, tb, wsf+OFF_TMAP);
  k_offscale<<<320, 256, 0, stream>>>(wsf+OFF_FEAT, ow, ob, sw, sb, wsf+OFF_OFFV, wsf+OFF_SCV);
  k_smooth<<<BB, 448, 0, stream>>>(input_seq, mask, wsf+OFF_GW, out1, out5);
  k_dist<<<dim3(128,BB), 64, 0, stream>>>(wsf, proto, out1, out5, wsf+OFF_OFFV, wsf+OFF_SCV, out2);
  k_argmin<<<1, 64, 0, stream>>>(out2, label, (int*)(wsf+OFF_IDX), out3, out4);
  k_out<<<dim3(7,BB), 64, 0, stream>>>(wsf, proto, wsf+OFF_OFFV, wsf+OFF_SCV, (int*)(wsf+OFF_IDX), out0);
}

// Round 3
// 755.937 us; speedup vs baseline: 1.4214x; 1.4214x over previous
//
#include <hip/hip_runtime.h>
#include <math.h>

#define TT 406
#define DD 10
#define PP 128
#define FF 128
#define BB 64
#define NCPc 12
#define NCc 28

// ---------------- workspace layout (float offsets) ----------------
constexpr size_t OFF_GW    = 0;                       // 406
constexpr size_t OFF_M24   = 448;                     // 406*24 = 9744
constexpr size_t OFF_BY    = 10240;                   // 406
constexpr size_t OFF_MEAN1 = 10688;                   // 128
constexpr size_t OFF_RSTD1 = 10816;                   // 128
constexpr size_t OFF_MEAN2 = 10944;                   // 256
constexpr size_t OFF_RSTD2 = 11200;                   // 256
constexpr size_t OFF_MEAN3 = 11456;                   // 128
constexpr size_t OFF_RSTD3 = 11584;                   // 128
constexpr size_t OFF_GAP   = 11712;                   // 64*128 = 8192
constexpr size_t OFF_FEAT  = 19904;                   // 8192
constexpr size_t OFF_IDX   = 28096;                   // 64 (int)
constexpr size_t OFF_TMAP  = 28160;                   // 8192*24 = 196608
constexpr size_t OFF_INVF  = OFF_TMAP;                // 961 f32, aliased: consumed by k_tps_rep
                                                      // BEFORE k_trans overwrites TMAP
constexpr size_t OFF_OFFV  = 224768;                  // 64*1280 = 81920
constexpr size_t OFF_SCV   = 306688;                  // 81920
constexpr size_t OFF_H1    = 388608;                  // 64*128*406 = 3325952 (aliased as h3)
constexpr size_t OFF_H2    = OFF_H1 + (size_t)BB*128*TT; // 64*256*406 = 6651904
// total = 10,366,464 floats = 41.5 MB

// ---------------- TPS constant helpers ----------------
__device__ __forceinline__ double tcpx(int n){ return -1.0 + 2.0*(double)(n>>1)/13.0; }
__device__ __forceinline__ double tcpy(int n){ return (n&1) ? 1.0 : -1.0; }
__device__ __forceinline__ double Ufun(double d2){ return d2 > 0.0 ? 0.5*d2*log(d2) : 0.0; }

// Parallel 31x31 inverse (Gauss-Jordan, f64, wave-parallel pivot argmax) + GW table.
__global__ __launch_bounds__(256) void k_tps_inv(float* __restrict__ ws){
  __shared__ double aug[31][62];
  __shared__ double fac[31];
  __shared__ int pivrow;
  int tid = threadIdx.x;

  // gaussian weight table GW[delta] = exp(-delta^2/98)
  for (int i = tid; i < TT; i += 256){
    float d = (float)i;
    ws[OFF_GW + i] = expf(-(d*d)/98.f);
  }

  // build [fk | I]
  for (int idx = tid; idx < 31*62; idx += 256){
    int r = idx/62, c = idx - (idx/62)*62;
    double v = 0.0;
    if (c < 31){
      if (r < 28 && c < 28){
        double dx = tcpx(r)-tcpx(c), dy = tcpy(r)-tcpy(c);
        v = Ufun(dx*dx + dy*dy);
      } else if (r < 28 && c == 28) v = 1.0;
      else if (r == 28 && c < 28)  v = 1.0;
      else if (r < 28 && c == 29)  v = tcpx(r);
      else if (r < 28 && c == 30)  v = tcpy(r);
      else if (r == 29 && c < 28)  v = tcpx(c);
      else if (r == 30 && c < 28)  v = tcpy(c);
      else v = 0.0;
    } else {
      v = ((c-31) == r) ? 1.0 : 0.0;
    }
    aug[r][c] = v;
  }
  __syncthreads();

  for (int k = 0; k < 31; ++k){
    // wave-parallel pivot argmax over rows k..30 (lowest-index max wins, like serial scan)
    if (tid < 64){
      double v = (tid >= k && tid < 31) ? fabs(aug[tid][k]) : -1.0;
      int idx = tid;
      for (int o = 32; o > 0; o >>= 1){
        double ov = __shfl_down(v, o);
        int oi = __shfl_down(idx, o);
        if (ov > v){ v = ov; idx = oi; }
      }
      if (tid == 0) pivrow = idx;
    }
    __syncthreads();
    int pr = pivrow;                      // uniform
    if (pr != k){
      for (int c = tid; c < 62; c += 256){
        double t = aug[k][c]; aug[k][c] = aug[pr][c]; aug[pr][c] = t;
      }
    }
    __syncthreads();
    double pk = aug[k][k];                // read by all before scaling writes
    __syncthreads();
    double pinv = 1.0/pk;
    for (int c = tid; c < 62; c += 256) aug[k][c] *= pinv;
    __syncthreads();
    for (int r = tid; r < 31; r += 256) fac[r] = aug[r][k];
    __syncthreads();
    for (int idx = tid; idx < 31*62; idx += 256){
      int r = idx/62, c = idx - (idx/62)*62;
      if (r != k) aug[r][c] -= fac[r]*aug[k][c];
    }
    __syncthreads();
  }

  // write INV (31x31) as f32
  for (int idx = tid; idx < 31*31; idx += 256){
    int n = idx/31, m = idx - (idx/31)*31;
    ws[OFF_INVF + (size_t)n*31 + m] = (float)aug[n][31+m];
  }
}

// M24[t][j] and base_y[t]: one thread per t, f32 (reference casts REP/INV to f32 anyway).
__global__ void k_tps_rep(float* __restrict__ ws){
  __shared__ float sinv[31*31];
  int tid = threadIdx.x;
  for (int i = tid; i < 31*31; i += 64) sinv[i] = ws[OFF_INVF + i];
  __syncthreads();
  int t = blockIdx.x*64 + tid;
  if (t >= TT) return;
  float yt = -1.f + 2.f*(float)t/405.f;
  float rep[31];
  #pragma unroll
  for (int n = 0; n < 28; ++n){
    float dx = -1.f - (-1.f + 2.f*(float)(n>>1)/13.f);
    float dy = yt - ((n&1) ? 1.f : -1.f);
    float d2 = dx*dx + dy*dy;
    rep[n] = (d2 > 0.f) ? 0.5f*d2*logf(d2) : 0.f;
  }
  rep[28] = 1.f; rep[29] = -1.f; rep[30] = yt;
  float Mm[28];
  #pragma unroll
  for (int m = 0; m < 28; ++m){
    float s = 0.f;
    #pragma unroll
    for (int n = 0; n < 31; ++n) s += rep[n]*sinv[n*31 + m];
    Mm[m] = s;
  }
  float base = 0.f;
  #pragma unroll
  for (int m = 0; m < 28; ++m) base += Mm[m]*((m&1) ? 1.f : -1.f);
  ws[OFF_BY + t] = base;
  #pragma unroll
  for (int j = 0; j < 24; ++j) ws[OFF_M24 + (size_t)t*24 + j] = Mm[j+2];
}

// ---------------- encoder ----------------
__global__ void k_conv1(const float* __restrict__ x, const float* __restrict__ w,
                        const float* __restrict__ bias, float* __restrict__ h1){
  int t  = blockIdx.x*256 + threadIdx.x;
  int co = blockIdx.y, b = blockIdx.z;
  if (t >= TT) return;
  float acc = bias[co];
  const float* wr = w + co*80;           // (co,ci,k) -> co*80+ci*8+k
  const float* xb = x + (size_t)b*TT*DD; // (b,t,d)
  #pragma unroll
  for (int k = 0; k < 8; ++k){
    int tt = t + k - 3;
    if (tt >= 0 && tt < TT){
      const float* xr = xb + tt*DD;
      #pragma unroll
      for (int ci = 0; ci < DD; ++ci) acc += xr[ci]*wr[ci*8+k];
    }
  }
  h1[((size_t)b*128 + co)*TT + t] = acc;
}

template<int C>
__global__ void k_bnstats(const float* __restrict__ h, float* __restrict__ mean, float* __restrict__ rstd){
  int c = blockIdx.x, tid = threadIdx.x;
  double s1 = 0.0, s2 = 0.0;
  for (int n = tid; n < BB*TT; n += 256){
    int b = n/TT, t = n - b*TT;
    double v = (double)h[((size_t)b*C + c)*TT + t];
    s1 += v; s2 += v*v;
  }
  for (int o = 32; o > 0; o >>= 1){ s1 += __shfl_down(s1, o); s2 += __shfl_down(s2, o); }
  __shared__ double sh1[4], sh2[4];
  int wv = tid >> 6, ln = tid & 63;
  if (ln == 0){ sh1[wv] = s1; sh2[wv] = s2; }
  __syncthreads();
  if (tid == 0){
    double a = sh1[0]+sh1[1]+sh1[2]+sh1[3];
    double q = sh2[0]+sh2[1]+sh2[2]+sh2[3];
    double m = a/(double)(BB*TT);
    double v = q/(double)(BB*TT) - m*m;
    mean[c] = (float)m;
    rstd[c] = (float)(1.0/sqrt(v + 1e-5));
  }
}

__global__ __launch_bounds__(256) void k_conv2(const float* __restrict__ h1, const float* __restrict__ w,
    const float* __restrict__ bias, const float* __restrict__ g1, const float* __restrict__ b1,
    const float* __restrict__ mean1, const float* __restrict__ rstd1, float* __restrict__ h2){
  __shared__ float xs[128][20];
  int b = blockIdx.y, t0 = blockIdx.x*16, tid = threadIdx.x;
  for (int idx = tid; idx < 128*20; idx += 256){
    int ci = idx/20, tt = idx - ci*20;
    int t = t0 - 2 + tt;
    float v = 0.f;
    if (t >= 0 && t < TT){
      float raw = h1[((size_t)b*128 + ci)*TT + t];
      v = fmaxf(g1[ci]*(raw - mean1[ci])*rstd1[ci] + b1[ci], 0.f);
    }
    xs[ci][tt] = v;
  }
  __syncthreads();
  int co = tid; // 256 output channels
  float acc[16];
  float bz = bias[co];
  #pragma unroll
  for (int i = 0; i < 16; ++i) acc[i] = bz;
  const float* wr = w + (size_t)co*640; // (co,ci,k) -> co*640+ci*5+k
  for (int ci = 0; ci < 128; ++ci){
    float xr[20];
    #pragma unroll
    for (int i = 0; i < 20; ++i) xr[i] = xs[ci][i];
    #pragma unroll
    for (int k = 0; k < 5; ++k){
      float wv = wr[ci*5 + k];
      #pragma unroll
      for (int i = 0; i < 16; ++i) acc[i] += wv*xr[i+k];
    }
  }
  float* outp = h2 + ((size_t)b*256 + co)*TT;
  #pragma unroll
  for (int i = 0; i < 16; ++i){ int t = t0 + i; if (t < TT) outp[t] = acc[i]; }
}

__global__ __launch_bounds__(128) void k_conv3(const float* __restrict__ h2, const float* __restrict__ w,
    const float* __restrict__ bias, const float* __restrict__ g2, const float* __restrict__ b2,
    const float* __restrict__ mean2, const float* __restrict__ rstd2, float* __restrict__ h3){
  __shared__ float xs[256][18];
  int b = blockIdx.y, t0 = blockIdx.x*16, tid = threadIdx.x;
  for (int idx = tid; idx < 256*18; idx += 128){
    int ci = idx/18, tt = idx - ci*18;
    int t = t0 - 1 + tt;
    float v = 0.f;
    if (t >= 0 && t < TT){
      float raw = h2[((size_t)b*256 + ci)*TT + t];
      v = fmaxf(g2[ci]*(raw - mean2[ci])*rstd2[ci] + b2[ci], 0.f);
    }
    xs[ci][tt] = v;
  }
  __syncthreads();
  int co = tid; // 128
  float acc[16];
  float bz = bias[co];
  #pragma unroll
  for (int i = 0; i < 16; ++i) acc[i] = bz;
  const float* wr = w + (size_t)co*768; // co*768+ci*3+k
  for (int ci = 0; ci < 256; ++ci){
    float xr[18];
    #pragma unroll
    for (int i = 0; i < 18; ++i) xr[i] = xs[ci][i];
    #pragma unroll
    for (int k = 0; k < 3; ++k){
      float wv = wr[ci*3 + k];
      #pragma unroll
      for (int i = 0; i < 16; ++i) acc[i] += wv*xr[i+k];
    }
  }
  float* outp = h3 + ((size_t)b*128 + co)*TT;
  #pragma unroll
  for (int i = 0; i < 16; ++i){ int t = t0 + i; if (t < TT) outp[t] = acc[i]; }
}

__global__ void k_gap(const float* __restrict__ h3, const float* __restrict__ g3, const float* __restrict__ b3,
                      const float* __restrict__ mean3, const float* __restrict__ rstd3, float* __restrict__ gap){
  int c = blockIdx.x, b = blockIdx.y, tid = threadIdx.x; // 64
  const float* row = h3 + ((size_t)b*128 + c)*TT;
  float m = mean3[c], r = rstd3[c], g = g3[c], bb = b3[c];
  float s = 0.f;
  for (int t = tid; t < TT; t += 64) s += fmaxf(g*(row[t]-m)*r + bb, 0.f);
  for (int o = 32; o > 0; o >>= 1) s += __shfl_down(s, o);
  if (tid == 0) gap[b*128 + c] = s/406.f;
}

__global__ void k_feat(const float* __restrict__ gap, const float* __restrict__ fw,
                       const float* __restrict__ fb, float* __restrict__ feat){
  int id = blockIdx.x*256 + threadIdx.x;
  if (id >= BB*128) return;
  int b = id >> 7, f = id & 127;
  float acc = fb[f];
  const float* gr = gap + b*128;
  for (int c = 0; c < 128; ++c) acc += gr[c]*fw[c*128 + f];
  feat[id] = acc;
}

// ---------------- heads ----------------
__global__ void k_trans(const float* __restrict__ feat, const float* __restrict__ tw,
                        const float* __restrict__ tb, float* __restrict__ tmap2){
  int id = blockIdx.x*256 + threadIdx.x; // 64*12*256 = 196608
  int b = id/3072; int rem = id - b*3072; int k = rem >> 8; int o = rem & 255;
  float acc = tb[k*256 + o];
  const float* fr = feat + b*128;
  const float* wr = tw + ((size_t)k*128)*256 + o;
  for (int f = 0; f < 128; ++f) acc += fr[f]*wr[f*256];
  float val = tanhf(acc)*5.f;
  int p = o & 127, j = 2*k + (o >> 7);
  tmap2[((size_t)b*128 + p)*24 + j] = val;
}

__global__ void k_offscale(const float* __restrict__ feat, const float* __restrict__ ow,
                           const float* __restrict__ ob, const float* __restrict__ sw,
                           const float* __restrict__ sb, float* __restrict__ offv, float* __restrict__ scv){
  int id = blockIdx.x*256 + threadIdx.x; // 64*1280
  if (id >= BB*1280) return;
  int b = id/1280, o = id - b*1280;
  const float* fr = feat + b*128;
  float a1 = ob[o], a2 = sb[o];
  for (int f = 0; f < 128; ++f){
    float fv = fr[f];
    a1 += fv*ow[f*1280 + o];
    a2 += fv*sw[f*1280 + o];
  }
  offv[id] = tanhf(a1);
  scv[id]  = tanhf(a2)*0.75f + 1.25f;
}

// ---------------- smoothing ----------------
__global__ __launch_bounds__(448) void k_smooth(const float* __restrict__ x, const int* __restrict__ mask,
    const float* __restrict__ gwt, float* __restrict__ out_inps, float* __restrict__ out_ms){
  int b = blockIdx.x, tid = threadIdx.x;
  __shared__ float xs[TT*DD];
  __shared__ float ms[TT];
  __shared__ float gw[TT];
  for (int i = tid; i < TT*DD; i += 448) xs[i] = x[(size_t)b*TT*DD + i];
  for (int i = tid; i < TT; i += 448){ ms[i] = (float)mask[b*TT + i]; gw[i] = gwt[i]; }
  __syncthreads();
  int t = tid;
  if (t >= TT) return;
  float a[10];
  #pragma unroll
  for (int d = 0; d < 10; ++d) a[d] = 0.f;
  float msum = 0.f;
  for (int i = 0; i < TT; ++i){
    float w = gw[(t > i) ? (t - i) : (i - t)];
    msum += w*ms[i];
    #pragma unroll
    for (int d = 0; d < 10; ++d) a[d] += w*xs[i*10 + d];
  }
  out_ms[b*TT + t] = msum;
  float den = (msum == 0.f) ? 1.f : msum;
  #pragma unroll
  for (int d = 0; d < 10; ++d) out_inps[((size_t)b*TT + t)*10 + d] = a[d]/den;
}

// ---------------- distance / argmin / output ----------------
__global__ void k_dist(const float* __restrict__ wsf, const float* __restrict__ proto,
                       const float* __restrict__ inps, const float* __restrict__ msf,
                       const float* __restrict__ offv, const float* __restrict__ scv,
                       float* __restrict__ dist){
  int p = blockIdx.x, b = blockIdx.y, tid = threadIdx.x; // 64 threads
  const float* M24 = wsf + OFF_M24;
  const float* by  = wsf + OFF_BY;
  const float* tm  = wsf + OFF_TMAP + ((size_t)b*128 + p)*24;
  float tmr[24];
  #pragma unroll
  for (int j = 0; j < 24; ++j) tmr[j] = tm[j];
  float ofr[10], scr[10];
  #pragma unroll
  for (int d = 0; d < 10; ++d){
    ofr[d] = offv[((size_t)b*128 + p)*10 + d];
    scr[d] = scv [((size_t)b*128 + p)*10 + d];
  }
  float acc = 0.f;
  for (int t = tid; t < TT; t += 64){
    const float* Mr = M24 + (size_t)t*24;
    float y = by[t];
    #pragma unroll
    for (int j = 0; j < 24; ++j) y += Mr[j]*tmr[j];
    float pos = (y + 1.f)*0.5f*405.f;
    pos = fminf(fmaxf(pos, 0.f), 405.f);
    int i0 = (int)pos;
    float w = pos - (float)i0;
    int i1 = min(i0 + 1, 405);
    const float* p0 = proto + ((size_t)p*TT + i0)*10;
    const float* p1 = proto + ((size_t)p*TT + i1)*10;
    const float* xr = inps + ((size_t)b*TT + t)*10;
    float s = 0.f;
    #pragma unroll
    for (int d = 0; d < 10; ++d){
      float val = (p0[d]*(1.f - w) + p1[d]*w + ofr[d])*scr[d];
      float df = xr[d] - val;
      s += df*df;
    }
    acc += msf[b*TT + t]*s;
  }
  for (int o = 32; o > 0; o >>= 1) acc += __shfl_down(acc, o);
  if (tid == 0) dist[b*128 + p] = acc;
}

__global__ void k_argmin(const float* __restrict__ dist, const int* __restrict__ label,
                         int* __restrict__ idxws, float* __restrict__ out3, float* __restrict__ out4){
  int b = threadIdx.x;
  if (b >= BB) return;
  const float* dr = dist + b*128;
  float best = dr[0]; int bi = 0;
  for (int p = 1; p < 128; ++p){
    float v = dr[p];
    if (v < best){ best = v; bi = p; }
  }
  idxws[b] = bi;
  out3[b] = (float)bi;
  out4[b] = (float)label[b];
}

__global__ void k_out(const float* __restrict__ wsf, const float* __restrict__ proto,
                      const float* __restrict__ offv, const float* __restrict__ scv,
                      const int* __restrict__ idxws, float* __restrict__ out0){
  int b = blockIdx.y;
  int t = blockIdx.x*64 + threadIdx.x;
  if (t >= TT) return;
  int p = idxws[b];
  const float* tm = wsf + OFF_TMAP + ((size_t)b*128 + p)*24;
  const float* Mr = wsf + OFF_M24 + (size_t)t*24;
  float y = wsf[OFF_BY + t];
  #pragma unroll
  for (int j = 0; j < 24; ++j) y += Mr[j]*tm[j];
  float pos = (y + 1.f)*0.5f*405.f;
  pos = fminf(fmaxf(pos, 0.f), 405.f);
  int i0 = (int)pos;
  float w = pos - (float)i0;
  int i1 = min(i0 + 1, 405);
  const float* p0 = proto + ((size_t)p*TT + i0)*10;
  const float* p1 = proto + ((size_t)p*TT + i1)*10;
  #pragma unroll
  for (int d = 0; d < 10; ++d){
    float val = (p0[d]*(1.f - w) + p1[d]*w + offv[((size_t)b*128 + p)*10 + d])*scv[((size_t)b*128 + p)*10 + d];
    out0[((size_t)b*TT + t)*10 + d] = val;
  }
}

// ---------------- launch ----------------
extern "C" void kernel_launch(void* const* d_in, const int* in_sizes, int n_in,
                              void* d_out, int out_size, void* d_ws, size_t ws_size,
                              hipStream_t stream){
  const float* input_seq = (const float*)d_in[0];
  const int*   label     = (const int*)  d_in[1];
  const int*   mask      = (const int*)  d_in[2];
  const float* proto     = (const float*)d_in[3];
  const float* c1w = (const float*)d_in[4];  const float* c1b = (const float*)d_in[5];
  const float* g1  = (const float*)d_in[6];  const float* b1  = (const float*)d_in[7];
  const float* c2w = (const float*)d_in[8];  const float* c2b = (const float*)d_in[9];
  const float* g2  = (const float*)d_in[10]; const float* b2  = (const float*)d_in[11];
  const float* c3w = (const float*)d_in[12]; const float* c3b = (const float*)d_in[13];
  const float* g3  = (const float*)d_in[14]; const float* b3  = (const float*)d_in[15];
  const float* fw  = (const float*)d_in[16]; const float* fb  = (const float*)d_in[17];
  const float* tw  = (const float*)d_in[18]; const float* tb  = (const float*)d_in[19];
  const float* ow  = (const float*)d_in[20]; const float* ob  = (const float*)d_in[21];
  const float* sw  = (const float*)d_in[22]; const float* sb  = (const float*)d_in[23];

  float* wsf = (float*)d_ws;
  float* out0 = (float*)d_out;             // (B,T,D) 259840
  float* out1 = out0 + 259840;             // inp_s   259840
  float* out2 = out0 + 519680;             // dist    8192
  float* out3 = out0 + 527872;             // indices 64
  float* out4 = out0 + 527936;             // label   64
  float* out5 = out0 + 528000;             // mask_s  25984

  float* h1 = wsf + OFF_H1;
  float* h2 = wsf + OFF_H2;
  float* h3 = h1; // h1 dead after conv2

  k_tps_inv<<<dim3(1), dim3(256), 0, stream>>>(wsf);
  k_tps_rep<<<dim3(7), dim3(64), 0, stream>>>(wsf);
  k_conv1<<<dim3(2,128,BB), 256, 0, stream>>>(input_seq, c1w, c1b, h1);
  k_bnstats<128><<<128, 256, 0, stream>>>(h1, wsf+OFF_MEAN1, wsf+OFF_RSTD1);
  k_conv2<<<dim3(26,BB), 256, 0, stream>>>(h1, c2w, c2b, g1, b1, wsf+OFF_MEAN1, wsf+OFF_RSTD1, h2);
  k_bnstats<256><<<256, 256, 0, stream>>>(h2, wsf+OFF_MEAN2, wsf+OFF_RSTD2);
  k_conv3<<<dim3(26,BB), 128, 0, stream>>>(h2, c3w, c3b, g2, b2, wsf+OFF_MEAN2, wsf+OFF_RSTD2, h3);
  k_bnstats<128><<<128, 256, 0, stream>>>(h3, wsf+OFF_MEAN3, wsf+OFF_RSTD3);
  k_gap<<<dim3(128,BB), 64, 0, stream>>>(h3, g3, b3, wsf+OFF_MEAN3, wsf+OFF_RSTD3, wsf+OFF_GAP);
  k_feat<<<32, 256, 0, stream>>>(wsf+OFF_GAP, fw, fb, wsf+OFF_FEAT);
  k_trans<<<768, 256, 0, stream>>>(wsf+OFF_FEAT, tw, tb, wsf+OFF_TMAP);
  k_offscale<<<320, 256, 0, stream>>>(wsf+OFF_FEAT, ow, ob, sw, sb, wsf+OFF_OFFV, wsf+OFF_SCV);
  k_smooth<<<BB, 448, 0, stream>>>(input_seq, mask, wsf+OFF_GW, out1, out5);
  k_dist<<<dim3(128,BB), 64, 0, stream>>>(wsf, proto, out1, out5, wsf+OFF_OFFV, wsf+OFF_SCV, out2);
  k_argmin<<<1, 64, 0, stream>>>(out2, label, (int*)(wsf+OFF_IDX), out3, out4);
  k_out<<<dim3(7,BB), 64, 0, stream>>>(wsf, proto, wsf+OFF_OFFV, wsf+OFF_SCV, (int*)(wsf+OFF_IDX), out0);
}

// Round 4
// 731.089 us; speedup vs baseline: 1.4697x; 1.0340x over previous
//
#include <hip/hip_runtime.h>
#include <math.h>

#define TT 406
#define DD 10
#define PP 128
#define FF 128
#define BB 64

// ---------------- workspace layout (float offsets) ----------------
constexpr size_t OFF_GW    = 0;                       // 406
constexpr size_t OFF_M24T  = 448;                     // [24][406] = 9744 (transposed)
constexpr size_t OFF_BY    = 10240;                   // 406
constexpr size_t OFF_MEAN1 = 10688;                   // 128
constexpr size_t OFF_RSTD1 = 10816;                   // 128
constexpr size_t OFF_MEAN2 = 10944;                   // 256
constexpr size_t OFF_RSTD2 = 11200;                   // 256
constexpr size_t OFF_MEAN3 = 11456;                   // 128
constexpr size_t OFF_RSTD3 = 11584;                   // 128
constexpr size_t OFF_GAP   = 11712;                   // 8192
constexpr size_t OFF_INVF  = OFF_GAP;                 // 961 f32 (dispatch 0-1, dead before k_gap)
constexpr size_t OFF_FEAT  = 19904;                   // 8192
constexpr size_t OFF_IDX   = 28096;                   // 64 (int)
constexpr size_t OFF_TMAP  = 28160;                   // 196608 (written by k_trans, late)
constexpr size_t OFF_WT2   = OFF_TMAP;                // 163840 f32: conv2 wT (dead before k_trans)
constexpr size_t OFF_OFFV  = 224768;                  // 81920 (written by k_offscale, late)
constexpr size_t OFF_WT3   = OFF_OFFV;                // 98304 f32: conv3 wT (spans OFFV+SCV head; dead before k_offscale)
constexpr size_t OFF_SCV   = 306688;                  // 81920
constexpr size_t OFF_H1    = 388608;                  // 64*128*406 = 3325952 (aliased as h3)
constexpr size_t OFF_H2    = OFF_H1 + (size_t)BB*128*TT; // 6651904
constexpr size_t OFF_INPT  = OFF_H2;                  // 259840: inpT[b][d][t] (h2 dead after conv3)
// total = 10,366,464 floats = 41.5 MB

// ---------------- TPS constant helpers ----------------
__device__ __forceinline__ double tcpx(int n){ return -1.0 + 2.0*(double)(n>>1)/13.0; }
__device__ __forceinline__ double tcpy(int n){ return (n&1) ? 1.0 : -1.0; }
__device__ __forceinline__ double Ufun(double d2){ return d2 > 0.0 ? 0.5*d2*log(d2) : 0.0; }

// Parallel 31x31 inverse (Gauss-Jordan, f64, wave-parallel pivot argmax) + GW table.
__global__ __launch_bounds__(256) void k_tps_inv(float* __restrict__ ws){
  __shared__ double aug[31][62];
  __shared__ double fac[31];
  __shared__ int pivrow;
  int tid = threadIdx.x;

  for (int i = tid; i < TT; i += 256){
    float d = (float)i;
    ws[OFF_GW + i] = expf(-(d*d)/98.f);
  }

  for (int idx = tid; idx < 31*62; idx += 256){
    int r = idx/62, c = idx - (idx/62)*62;
    double v = 0.0;
    if (c < 31){
      if (r < 28 && c < 28){
        double dx = tcpx(r)-tcpx(c), dy = tcpy(r)-tcpy(c);
        v = Ufun(dx*dx + dy*dy);
      } else if (r < 28 && c == 28) v = 1.0;
      else if (r == 28 && c < 28)  v = 1.0;
      else if (r < 28 && c == 29)  v = tcpx(r);
      else if (r < 28 && c == 30)  v = tcpy(r);
      else if (r == 29 && c < 28)  v = tcpx(c);
      else if (r == 30 && c < 28)  v = tcpy(c);
      else v = 0.0;
    } else {
      v = ((c-31) == r) ? 1.0 : 0.0;
    }
    aug[r][c] = v;
  }
  __syncthreads();

  for (int k = 0; k < 31; ++k){
    if (tid < 64){
      double v = (tid >= k && tid < 31) ? fabs(aug[tid][k]) : -1.0;
      int idx = tid;
      for (int o = 32; o > 0; o >>= 1){
        double ov = __shfl_down(v, o);
        int oi = __shfl_down(idx, o);
        if (ov > v){ v = ov; idx = oi; }
      }
      if (tid == 0) pivrow = idx;
    }
    __syncthreads();
    int pr = pivrow;
    if (pr != k){
      for (int c = tid; c < 62; c += 256){
        double t = aug[k][c]; aug[k][c] = aug[pr][c]; aug[pr][c] = t;
      }
    }
    __syncthreads();
    double pk = aug[k][k];
    __syncthreads();
    double pinv = 1.0/pk;
    for (int c = tid; c < 62; c += 256) aug[k][c] *= pinv;
    __syncthreads();
    for (int r = tid; r < 31; r += 256) fac[r] = aug[r][k];
    __syncthreads();
    for (int idx = tid; idx < 31*62; idx += 256){
      int r = idx/62, c = idx - (idx/62)*62;
      if (r != k) aug[r][c] -= fac[r]*aug[k][c];
    }
    __syncthreads();
  }

  for (int idx = tid; idx < 31*31; idx += 256){
    int n = idx/31, m = idx - (idx/31)*31;
    ws[OFF_INVF + (size_t)n*31 + m] = (float)aug[n][31+m];
  }
}

// M24T[j][t] and base_y[t]: one thread per t, f32 (reference casts REP/INV to f32 anyway).
__global__ void k_tps_rep(float* __restrict__ ws){
  __shared__ float sinv[31*31];
  int tid = threadIdx.x;
  for (int i = tid; i < 31*31; i += 64) sinv[i] = ws[OFF_INVF + i];
  __syncthreads();
  int t = blockIdx.x*64 + tid;
  if (t >= TT) return;
  float yt = -1.f + 2.f*(float)t/405.f;
  float rep[31];
  #pragma unroll
  for (int n = 0; n < 28; ++n){
    float dx = -1.f - (-1.f + 2.f*(float)(n>>1)/13.f);
    float dy = yt - ((n&1) ? 1.f : -1.f);
    float d2 = dx*dx + dy*dy;
    rep[n] = (d2 > 0.f) ? 0.5f*d2*logf(d2) : 0.f;
  }
  rep[28] = 1.f; rep[29] = -1.f; rep[30] = yt;
  float Mm[28];
  #pragma unroll
  for (int m = 0; m < 28; ++m){
    float s = 0.f;
    #pragma unroll
    for (int n = 0; n < 31; ++n) s += rep[n]*sinv[n*31 + m];
    Mm[m] = s;
  }
  float base = 0.f;
  #pragma unroll
  for (int m = 0; m < 28; ++m) base += Mm[m]*((m&1) ? 1.f : -1.f);
  ws[OFF_BY + t] = base;
  #pragma unroll
  for (int j = 0; j < 24; ++j) ws[OFF_M24T + (size_t)j*TT + t] = Mm[j+2];
}

// weight transpose: wT2[(ci*5+k)*256+co], wT3[(ci*3+k)*128+co]
__global__ void k_wt(const float* __restrict__ w2, const float* __restrict__ w3, float* __restrict__ ws){
  int idx = blockIdx.x*256 + threadIdx.x;
  if (idx < 163840){
    int ck = idx >> 8, co = idx & 255;
    ws[OFF_WT2 + idx] = w2[co*640 + ck];
  } else if (idx < 163840 + 98304){
    int j = idx - 163840;
    int ck = j >> 7, co = j & 127;
    ws[OFF_WT3 + j] = w3[co*768 + ck];
  }
}

// ---------------- encoder ----------------
__global__ void k_conv1(const float* __restrict__ x, const float* __restrict__ w,
                        const float* __restrict__ bias, float* __restrict__ h1){
  int t  = blockIdx.x*256 + threadIdx.x;
  int co = blockIdx.y, b = blockIdx.z;
  if (t >= TT) return;
  float acc = bias[co];
  const float* wr = w + co*80;
  const float* xb = x + (size_t)b*TT*DD;
  #pragma unroll
  for (int k = 0; k < 8; ++k){
    int tt = t + k - 3;
    if (tt >= 0 && tt < TT){
      const float* xr = xb + tt*DD;
      #pragma unroll
      for (int ci = 0; ci < DD; ++ci) acc += xr[ci]*wr[ci*8+k];
    }
  }
  h1[((size_t)b*128 + co)*TT + t] = acc;
}

template<int C>
__global__ void k_bnstats(const float* __restrict__ h, float* __restrict__ mean, float* __restrict__ rstd){
  int c = blockIdx.x, tid = threadIdx.x;
  double s1 = 0.0, s2 = 0.0;
  for (int n = tid; n < BB*TT; n += 256){
    int b = n/TT, t = n - b*TT;
    double v = (double)h[((size_t)b*C + c)*TT + t];
    s1 += v; s2 += v*v;
  }
  for (int o = 32; o > 0; o >>= 1){ s1 += __shfl_down(s1, o); s2 += __shfl_down(s2, o); }
  __shared__ double sh1[4], sh2[4];
  int wv = tid >> 6, ln = tid & 63;
  if (ln == 0){ sh1[wv] = s1; sh2[wv] = s2; }
  __syncthreads();
  if (tid == 0){
    double a = sh1[0]+sh1[1]+sh1[2]+sh1[3];
    double q = sh2[0]+sh2[1]+sh2[2]+sh2[3];
    double m = a/(double)(BB*TT);
    double v = q/(double)(BB*TT) - m*m;
    mean[c] = (float)m;
    rstd[c] = (float)(1.0/sqrt(v + 1e-5));
  }
}

// conv2: 32-t tile, coalesced transposed weights. block 256 thr = one co each.
__global__ __launch_bounds__(256) void k_conv2(const float* __restrict__ h1, const float* __restrict__ wT,
    const float* __restrict__ bias, const float* __restrict__ g1, const float* __restrict__ b1,
    const float* __restrict__ mean1, const float* __restrict__ rstd1, float* __restrict__ h2){
  __shared__ float xs[128][36];
  int b = blockIdx.y, t0 = blockIdx.x*32, tid = threadIdx.x;
  for (int idx = tid; idx < 128*36; idx += 256){
    int ci = idx/36, tt = idx - ci*36;
    int t = t0 - 2 + tt;
    float v = 0.f;
    if (t >= 0 && t < TT){
      float raw = h1[((size_t)b*128 + ci)*TT + t];
      v = fmaxf(g1[ci]*(raw - mean1[ci])*rstd1[ci] + b1[ci], 0.f);
    }
    xs[ci][tt] = v;
  }
  __syncthreads();
  int co = tid;
  float acc[32];
  float bz = bias[co];
  #pragma unroll
  for (int i = 0; i < 32; ++i) acc[i] = bz;
  for (int ci = 0; ci < 128; ++ci){
    float xr[36];
    #pragma unroll
    for (int i = 0; i < 36; ++i) xr[i] = xs[ci][i];
    #pragma unroll
    for (int k = 0; k < 5; ++k){
      float wv = wT[(ci*5 + k)*256 + co];
      #pragma unroll
      for (int i = 0; i < 32; ++i) acc[i] += wv*xr[i+k];
    }
  }
  float* outp = h2 + ((size_t)b*256 + co)*TT;
  #pragma unroll
  for (int i = 0; i < 32; ++i){ int t = t0 + i; if (t < TT) outp[t] = acc[i]; }
}

// conv3: 32-t tile split in two 16-t halves; co = tid&127, half = tid>>7.
__global__ __launch_bounds__(256) void k_conv3(const float* __restrict__ h2, const float* __restrict__ wT,
    const float* __restrict__ bias, const float* __restrict__ g2, const float* __restrict__ b2,
    const float* __restrict__ mean2, const float* __restrict__ rstd2, float* __restrict__ h3){
  __shared__ float xs[256][36];
  int b = blockIdx.y, t0 = blockIdx.x*32, tid = threadIdx.x;
  for (int idx = tid; idx < 256*36; idx += 256){
    int ci = idx/36, tt = idx - ci*36;
    int t = t0 - 1 + tt;
    float v = 0.f;
    if (t >= 0 && t < TT){
      float raw = h2[((size_t)b*256 + ci)*TT + t];
      v = fmaxf(g2[ci]*(raw - mean2[ci])*rstd2[ci] + b2[ci], 0.f);
    }
    xs[ci][tt] = v;
  }
  __syncthreads();
  int co = tid & 127, th = tid >> 7;
  float acc[16];
  float bz = bias[co];
  #pragma unroll
  for (int i = 0; i < 16; ++i) acc[i] = bz;
  for (int ci = 0; ci < 256; ++ci){
    float xr[18];
    #pragma unroll
    for (int i = 0; i < 18; ++i) xr[i] = xs[ci][th*16 + i];
    #pragma unroll
    for (int k = 0; k < 3; ++k){
      float wv = wT[(ci*3 + k)*128 + co];
      #pragma unroll
      for (int i = 0; i < 16; ++i) acc[i] += wv*xr[i+k];
    }
  }
  int tb = t0 + th*16;
  float* outp = h3 + ((size_t)b*128 + co)*TT;
  #pragma unroll
  for (int i = 0; i < 16; ++i){ int t = tb + i; if (t < TT) outp[t] = acc[i]; }
}

__global__ void k_gap(const float* __restrict__ h3, const float* __restrict__ g3, const float* __restrict__ b3,
                      const float* __restrict__ mean3, const float* __restrict__ rstd3, float* __restrict__ gap){
  int c = blockIdx.x, b = blockIdx.y, tid = threadIdx.x; // 64
  const float* row = h3 + ((size_t)b*128 + c)*TT;
  float m = mean3[c], r = rstd3[c], g = g3[c], bb = b3[c];
  float s = 0.f;
  for (int t = tid; t < TT; t += 64) s += fmaxf(g*(row[t]-m)*r + bb, 0.f);
  for (int o = 32; o > 0; o >>= 1) s += __shfl_down(s, o);
  if (tid == 0) gap[b*128 + c] = s/406.f;
}

__global__ void k_feat(const float* __restrict__ gap, const float* __restrict__ fw,
                       const float* __restrict__ fb, float* __restrict__ feat){
  int id = blockIdx.x*256 + threadIdx.x;
  if (id >= BB*128) return;
  int b = id >> 7, f = id & 127;
  float acc = fb[f];
  const float* gr = gap + b*128;
  for (int c = 0; c < 128; ++c) acc += gr[c]*fw[c*128 + f];
  feat[id] = acc;
}

// ---------------- heads ----------------
__global__ void k_trans(const float* __restrict__ feat, const float* __restrict__ tw,
                        const float* __restrict__ tb, float* __restrict__ tmap2){
  int id = blockIdx.x*256 + threadIdx.x;
  int b = id/3072; int rem = id - b*3072; int k = rem >> 8; int o = rem & 255;
  float acc = tb[k*256 + o];
  const float* fr = feat + b*128;
  const float* wr = tw + ((size_t)k*128)*256 + o;
  for (int f = 0; f < 128; ++f) acc += fr[f]*wr[f*256];
  float val = tanhf(acc)*5.f;
  int p = o & 127, j = 2*k + (o >> 7);
  tmap2[((size_t)b*128 + p)*24 + j] = val;
}

__global__ void k_offscale(const float* __restrict__ feat, const float* __restrict__ ow,
                           const float* __restrict__ ob, const float* __restrict__ sw,
                           const float* __restrict__ sb, float* __restrict__ offv, float* __restrict__ scv){
  int id = blockIdx.x*256 + threadIdx.x;
  if (id >= BB*1280) return;
  int b = id/1280, o = id - b*1280;
  const float* fr = feat + b*128;
  float a1 = ob[o], a2 = sb[o];
  for (int f = 0; f < 128; ++f){
    float fv = fr[f];
    a1 += fv*ow[f*1280 + o];
    a2 += fv*sw[f*1280 + o];
  }
  offv[id] = tanhf(a1);
  scv[id]  = tanhf(a2)*0.75f + 1.25f;
}

// ---------------- smoothing (4 t-chunks per b; also writes transposed copy) ----------------
__global__ __launch_bounds__(128) void k_smooth(const float* __restrict__ x, const int* __restrict__ mask,
    const float* __restrict__ gwt, float* __restrict__ out_inps, float* __restrict__ out_ms,
    float* __restrict__ inpT){
  int b = blockIdx.x, tid = threadIdx.x;
  __shared__ float xs[TT*DD];
  __shared__ float ms[TT];
  __shared__ float gw[TT];
  for (int i = tid; i < TT*DD; i += 128) xs[i] = x[(size_t)b*TT*DD + i];
  for (int i = tid; i < TT; i += 128){ ms[i] = (float)mask[b*TT + i]; gw[i] = gwt[i]; }
  __syncthreads();
  if (tid >= 102) return;
  int t = blockIdx.y*102 + tid;
  if (t >= TT) return;
  float a[10];
  #pragma unroll
  for (int d = 0; d < 10; ++d) a[d] = 0.f;
  float msum = 0.f;
  for (int i = 0; i < TT; ++i){
    float w = gw[(t > i) ? (t - i) : (i - t)];
    msum += w*ms[i];
    #pragma unroll
    for (int d = 0; d < 10; ++d) a[d] += w*xs[i*10 + d];
  }
  out_ms[b*TT + t] = msum;
  float den = (msum == 0.f) ? 1.f : msum;
  #pragma unroll
  for (int d = 0; d < 10; ++d){
    float v = a[d]/den;
    out_inps[((size_t)b*TT + t)*10 + d] = v;
    inpT[(size_t)b*TT*DD + (size_t)d*TT + t] = v;
  }
}

// ---------------- distance / argmin / output ----------------
__global__ __launch_bounds__(64) void k_dist(const float* __restrict__ wsf, const float* __restrict__ proto,
                       const float* __restrict__ inpT, const float* __restrict__ msf,
                       const float* __restrict__ offv, const float* __restrict__ scv,
                       float* __restrict__ dist){
  int p = blockIdx.x, b = blockIdx.y, tid = threadIdx.x; // 64 threads
  __shared__ float pr[TT*DD]; // 16.2 KB: prototype p staged
  for (int i = tid; i < TT*DD; i += 64) pr[i] = proto[(size_t)p*TT*DD + i];
  const float* M24 = wsf + OFF_M24T;
  const float* by  = wsf + OFF_BY;
  const float* tm  = wsf + OFF_TMAP + ((size_t)b*128 + p)*24;
  float tmr[24];
  #pragma unroll
  for (int j = 0; j < 24; ++j) tmr[j] = tm[j];
  float ofr[10], scr[10];
  #pragma unroll
  for (int d = 0; d < 10; ++d){
    ofr[d] = offv[((size_t)b*128 + p)*10 + d];
    scr[d] = scv [((size_t)b*128 + p)*10 + d];
  }
  __syncthreads();
  float acc = 0.f;
  for (int t = tid; t < TT; t += 64){
    float y = by[t];
    #pragma unroll
    for (int j = 0; j < 24; ++j) y += M24[j*TT + t]*tmr[j];
    float pos = (y + 1.f)*0.5f*405.f;
    pos = fminf(fmaxf(pos, 0.f), 405.f);
    int i0 = (int)pos;
    float w = pos - (float)i0;
    int i1 = min(i0 + 1, 405);
    const float* p0 = pr + i0*10;
    const float* p1 = pr + i1*10;
    float s = 0.f;
    #pragma unroll
    for (int d = 0; d < 10; ++d){
      float val = (p0[d]*(1.f - w) + p1[d]*w + ofr[d])*scr[d];
      float df = inpT[(size_t)b*TT*DD + (size_t)d*TT + t] - val;
      s += df*df;
    }
    acc += msf[b*TT + t]*s;
  }
  for (int o = 32; o > 0; o >>= 1) acc += __shfl_down(acc, o);
  if (tid == 0) dist[b*128 + p] = acc;
}

__global__ void k_argmin(const float* __restrict__ dist, const int* __restrict__ label,
                         int* __restrict__ idxws, float* __restrict__ out3, float* __restrict__ out4){
  int b = threadIdx.x;
  if (b >= BB) return;
  const float* dr = dist + b*128;
  float best = dr[0]; int bi = 0;
  for (int p = 1; p < 128; ++p){
    float v = dr[p];
    if (v < best){ best = v; bi = p; }
  }
  idxws[b] = bi;
  out3[b] = (float)bi;
  out4[b] = (float)label[b];
}

__global__ void k_out(const float* __restrict__ wsf, const float* __restrict__ proto,
                      const float* __restrict__ offv, const float* __restrict__ scv,
                      const int* __restrict__ idxws, float* __restrict__ out0){
  int b = blockIdx.y;
  int t = blockIdx.x*64 + threadIdx.x;
  if (t >= TT) return;
  int p = idxws[b];
  const float* tm = wsf + OFF_TMAP + ((size_t)b*128 + p)*24;
  const float* M24 = wsf + OFF_M24T;
  float y = wsf[OFF_BY + t];
  #pragma unroll
  for (int j = 0; j < 24; ++j) y += M24[j*TT + t]*tm[j];
  float pos = (y + 1.f)*0.5f*405.f;
  pos = fminf(fmaxf(pos, 0.f), 405.f);
  int i0 = (int)pos;
  float w = pos - (float)i0;
  int i1 = min(i0 + 1, 405);
  const float* p0 = proto + ((size_t)p*TT + i0)*10;
  const float* p1 = proto + ((size_t)p*TT + i1)*10;
  #pragma unroll
  for (int d = 0; d < 10; ++d){
    float val = (p0[d]*(1.f - w) + p1[d]*w + offv[((size_t)b*128 + p)*10 + d])*scv[((size_t)b*128 + p)*10 + d];
    out0[((size_t)b*TT + t)*10 + d] = val;
  }
}

// ---------------- launch ----------------
extern "C" void kernel_launch(void* const* d_in, const int* in_sizes, int n_in,
                              void* d_out, int out_size, void* d_ws, size_t ws_size,
                              hipStream_t stream){
  const float* input_seq = (const float*)d_in[0];
  const int*   label     = (const int*)  d_in[1];
  const int*   mask      = (const int*)  d_in[2];
  const float* proto     = (const float*)d_in[3];
  const float* c1w = (const float*)d_in[4];  const float* c1b = (const float*)d_in[5];
  const float* g1  = (const float*)d_in[6];  const float* b1  = (const float*)d_in[7];
  const float* c2w = (const float*)d_in[8];  const float* c2b = (const float*)d_in[9];
  const float* g2  = (const float*)d_in[10]; const float* b2  = (const float*)d_in[11];
  const float* c3w = (const float*)d_in[12]; const float* c3b = (const float*)d_in[13];
  const float* g3  = (const float*)d_in[14]; const float* b3  = (const float*)d_in[15];
  const float* fw  = (const float*)d_in[16]; const float* fb  = (const float*)d_in[17];
  const float* tw  = (const float*)d_in[18]; const float* tb  = (const float*)d_in[19];
  const float* ow  = (const float*)d_in[20]; const float* ob  = (const float*)d_in[21];
  const float* sw  = (const float*)d_in[22]; const float* sb  = (const float*)d_in[23];

  float* wsf = (float*)d_ws;
  float* out0 = (float*)d_out;             // (B,T,D) 259840
  float* out1 = out0 + 259840;             // inp_s   259840
  float* out2 = out0 + 519680;             // dist    8192
  float* out3 = out0 + 527872;             // indices 64
  float* out4 = out0 + 527936;             // label   64
  float* out5 = out0 + 528000;             // mask_s  25984

  float* h1 = wsf + OFF_H1;
  float* h2 = wsf + OFF_H2;
  float* h3 = h1; // h1 dead after conv2
  float* inpT = wsf + OFF_INPT; // h2 dead after conv3

  k_tps_inv<<<dim3(1), dim3(256), 0, stream>>>(wsf);
  k_tps_rep<<<dim3(7), dim3(64), 0, stream>>>(wsf);
  k_wt<<<dim3(1024), dim3(256), 0, stream>>>(c2w, c3w, wsf);
  k_conv1<<<dim3(2,128,BB), 256, 0, stream>>>(input_seq, c1w, c1b, h1);
  k_bnstats<128><<<128, 256, 0, stream>>>(h1, wsf+OFF_MEAN1, wsf+OFF_RSTD1);
  k_conv2<<<dim3(13,BB), 256, 0, stream>>>(h1, wsf+OFF_WT2, c2b, g1, b1, wsf+OFF_MEAN1, wsf+OFF_RSTD1, h2);
  k_bnstats<256><<<256, 256, 0, stream>>>(h2, wsf+OFF_MEAN2, wsf+OFF_RSTD2);
  k_conv3<<<dim3(13,BB), 256, 0, stream>>>(h2, wsf+OFF_WT3, c3b, g2, b2, wsf+OFF_MEAN2, wsf+OFF_RSTD2, h3);
  k_bnstats<128><<<128, 256, 0, stream>>>(h3, wsf+OFF_MEAN3, wsf+OFF_RSTD3);
  k_gap<<<dim3(128,BB), 64, 0, stream>>>(h3, g3, b3, wsf+OFF_MEAN3, wsf+OFF_RSTD3, wsf+OFF_GAP);
  k_feat<<<32, 256, 0, stream>>>(wsf+OFF_GAP, fw, fb, wsf+OFF_FEAT);
  k_trans<<<768, 256, 0, stream>>>(wsf+OFF_FEAT, tw, tb, wsf+OFF_TMAP);
  k_offscale<<<320, 256, 0, stream>>>(wsf+OFF_FEAT, ow, ob, sw, sb, wsf+OFF_OFFV, wsf+OFF_SCV);
  k_smooth<<<dim3(BB,4), 128, 0, stream>>>(input_seq, mask, wsf+OFF_GW, out1, out5, inpT);
  k_dist<<<dim3(128,BB), 64, 0, stream>>>(wsf, proto, inpT, out5, wsf+OFF_OFFV, wsf+OFF_SCV, out2);
  k_argmin<<<1, 64, 0, stream>>>(out2, label, (int*)(wsf+OFF_IDX), out3, out4);
  k_out<<<dim3(7,BB), 64, 0, stream>>>(wsf, proto, wsf+OFF_OFFV, wsf+OFF_SCV, (int*)(wsf+OFF_IDX), out0);
}

// Round 8
// 643.243 us; speedup vs baseline: 1.6704x; 1.1366x over previous
//
#include <hip/hip_runtime.h>
#include <math.h>

#define TT 406
#define DD 10
#define PP 128
#define FF 128
#define BB 64

using bf16x8 = __attribute__((ext_vector_type(8))) short;
using f32x4  = __attribute__((ext_vector_type(4))) float;

// ---------------- workspace layout (float offsets) ----------------
constexpr size_t OFF_GW    = 0;                       // 406
constexpr size_t OFF_M24T  = 448;                     // [24][406] = 9744 (transposed)
constexpr size_t OFF_BY    = 10240;                   // 406
constexpr size_t OFF_MEAN1 = 10688;                   // 128
constexpr size_t OFF_RSTD1 = 10816;                   // 128
constexpr size_t OFF_MEAN2 = 10944;                   // 256
constexpr size_t OFF_RSTD2 = 11200;                   // 256
constexpr size_t OFF_MEAN3 = 11456;                   // 128
constexpr size_t OFF_RSTD3 = 11584;                   // 128
constexpr size_t OFF_GAP   = 11712;                   // 8192
constexpr size_t OFF_INVF  = OFF_GAP;                 // 961 f32 (dead before k_gap)
constexpr size_t OFF_FEAT  = 19904;                   // 8192
constexpr size_t OFF_IDX   = 28096;                   // 64 (int)
constexpr size_t OFF_TMAP  = 28160;                   // 196608 (written by k_trans, late)
// bf16 weight planes (ushort units, based at OFF_TMAP): dead before k_trans/k_offscale write
//   WH2: 163840 ush | WL2: 163840 | WH3: 98304 | WL3: 98304  => 262144 floats [28160,290304)
constexpr size_t OFF_OFFV  = 224768;                  // 81920 (written by k_offscale, late)
constexpr size_t OFF_SCV   = 306688;                  // 81920
constexpr size_t OFF_H1    = 388608;                  // 64*128*406 = 3325952 (aliased as h3)
constexpr size_t OFF_H2    = OFF_H1 + (size_t)BB*128*TT; // 6651904
constexpr size_t OFF_INPT  = OFF_H2;                  // 259840: inpT[b][d][t] (h2 dead after conv3)
// total = 10,366,464 floats = 41.5 MB (unchanged footprint)

__device__ __forceinline__ f32x4 mfma_bf16(bf16x8 a, bf16x8 b, f32x4 c){
  return __builtin_amdgcn_mfma_f32_16x16x32_bf16(a, b, c, 0, 0, 0);
}

// split f32 -> bf16 hi (truncate) + bf16 lo (RNE of remainder): hi+lo ~ 24-bit mantissa
__device__ __forceinline__ void fsplit(float x, unsigned short &h, unsigned short &l){
  union { float f; unsigned int u; } a; a.f = x;
  unsigned short hh = (unsigned short)(a.u >> 16);
  union { float f; unsigned int u; } hf; hf.u = ((unsigned int)hh) << 16;
  float r = x - hf.f;
  union { float f; unsigned int u; } bb; bb.f = r;
  unsigned int u = bb.u;
  unsigned int rnd = u + 0x7FFFu + ((u >> 16) & 1u);
  h = hh; l = (unsigned short)(rnd >> 16);
}

// ---------------- TPS constant helpers ----------------
__device__ __forceinline__ double tcpx(int n){ return -1.0 + 2.0*(double)(n>>1)/13.0; }
__device__ __forceinline__ double tcpy(int n){ return (n&1) ? 1.0 : -1.0; }
__device__ __forceinline__ double Ufun(double d2){ return d2 > 0.0 ? 0.5*d2*log(d2) : 0.0; }

__global__ __launch_bounds__(256) void k_tps_inv(float* __restrict__ ws){
  __shared__ double aug[31][62];
  __shared__ double fac[31];
  __shared__ int pivrow;
  int tid = threadIdx.x;

  for (int i = tid; i < TT; i += 256){
    float d = (float)i;
    ws[OFF_GW + i] = expf(-(d*d)/98.f);
  }

  for (int idx = tid; idx < 31*62; idx += 256){
    int r = idx/62, c = idx - (idx/62)*62;
    double v = 0.0;
    if (c < 31){
      if (r < 28 && c < 28){
        double dx = tcpx(r)-tcpx(c), dy = tcpy(r)-tcpy(c);
        v = Ufun(dx*dx + dy*dy);
      } else if (r < 28 && c == 28) v = 1.0;
      else if (r == 28 && c < 28)  v = 1.0;
      else if (r < 28 && c == 29)  v = tcpx(r);
      else if (r < 28 && c == 30)  v = tcpy(r);
      else if (r == 29 && c < 28)  v = tcpx(c);
      else if (r == 30 && c < 28)  v = tcpy(c);
      else v = 0.0;
    } else {
      v = ((c-31) == r) ? 1.0 : 0.0;
    }
    aug[r][c] = v;
  }
  __syncthreads();

  for (int k = 0; k < 31; ++k){
    if (tid < 64){
      double v = (tid >= k && tid < 31) ? fabs(aug[tid][k]) : -1.0;
      int idx = tid;
      for (int o = 32; o > 0; o >>= 1){
        double ov = __shfl_down(v, o);
        int oi = __shfl_down(idx, o);
        if (ov > v){ v = ov; idx = oi; }
      }
      if (tid == 0) pivrow = idx;
    }
    __syncthreads();
    int pr = pivrow;
    if (pr != k){
      for (int c = tid; c < 62; c += 256){
        double t = aug[k][c]; aug[k][c] = aug[pr][c]; aug[pr][c] = t;
      }
    }
    __syncthreads();
    double pk = aug[k][k];
    __syncthreads();
    double pinv = 1.0/pk;
    for (int c = tid; c < 62; c += 256) aug[k][c] *= pinv;
    __syncthreads();
    for (int r = tid; r < 31; r += 256) fac[r] = aug[r][k];
    __syncthreads();
    for (int idx = tid; idx < 31*62; idx += 256){
      int r = idx/62, c = idx - (idx/62)*62;
      if (r != k) aug[r][c] -= fac[r]*aug[k][c];
    }
    __syncthreads();
  }

  for (int idx = tid; idx < 31*31; idx += 256){
    int n = idx/31, m = idx - (idx/31)*31;
    ws[OFF_INVF + (size_t)n*31 + m] = (float)aug[n][31+m];
  }
}

__global__ void k_tps_rep(float* __restrict__ ws){
  __shared__ float sinv[31*31];
  int tid = threadIdx.x;
  for (int i = tid; i < 31*31; i += 64) sinv[i] = ws[OFF_INVF + i];
  __syncthreads();
  int t = blockIdx.x*64 + tid;
  if (t >= TT) return;
  float yt = -1.f + 2.f*(float)t/405.f;
  float rep[31];
  #pragma unroll
  for (int n = 0; n < 28; ++n){
    float dx = -1.f - (-1.f + 2.f*(float)(n>>1)/13.f);
    float dy = yt - ((n&1) ? 1.f : -1.f);
    float d2 = dx*dx + dy*dy;
    rep[n] = (d2 > 0.f) ? 0.5f*d2*logf(d2) : 0.f;
  }
  rep[28] = 1.f; rep[29] = -1.f; rep[30] = yt;
  float Mm[28];
  #pragma unroll
  for (int m = 0; m < 28; ++m){
    float s = 0.f;
    #pragma unroll
    for (int n = 0; n < 31; ++n) s += rep[n]*sinv[n*31 + m];
    Mm[m] = s;
  }
  float base = 0.f;
  #pragma unroll
  for (int m = 0; m < 28; ++m) base += Mm[m]*((m&1) ? 1.f : -1.f);
  ws[OFF_BY + t] = base;
  #pragma unroll
  for (int j = 0; j < 24; ++j) ws[OFF_M24T + (size_t)j*TT + t] = Mm[j+2];
}

// pack conv2/conv3 weights into MFMA A-fragment order, bf16 hi/lo planes.
// WH2[c(4)][k(5)][sub(4)][co(256)][b(8)], ci = c*32+sub*8+b ; same scheme for conv3.
__global__ void k_wprep(const float* __restrict__ w2, const float* __restrict__ w3,
                        unsigned short* __restrict__ wu){
  int idx = blockIdx.x*256 + threadIdx.x;
  if (idx >= 262144) return;
  float x; int dh, dl;
  if (idx < 163840){
    int bb = idx & 7, r = idx >> 3;
    int co = r & 255; r >>= 8;
    int sub = r & 3; r >>= 2;           // r = c*5+k
    int k = r % 5, c = r / 5;
    int ci = c*32 + sub*8 + bb;
    x = w2[co*640 + ci*5 + k];
    dh = idx; dl = idx + 163840;
  } else {
    int j = idx - 163840;
    int bb = j & 7, r = j >> 3;
    int co = r & 127; r >>= 7;
    int sub = r & 3; r >>= 2;           // r = c*3+k
    int k = r % 3, c = r / 3;
    int ci = c*32 + sub*8 + bb;
    x = w3[co*768 + ci*3 + k];
    dh = 327680 + j; dl = 327680 + 98304 + j;
  }
  unsigned short h, l; fsplit(x, h, l);
  wu[dh] = h; wu[dl] = l;
}

// ---------------- conv1: weights in regs, x in LDS, transposed store ----------------
__global__ __launch_bounds__(256) void k_conv1(const float* __restrict__ x, const float* __restrict__ w,
                        const float* __restrict__ bias, float* __restrict__ h1){
  __shared__ float xs[39][10];
  __shared__ float outb[128][33];
  int b = blockIdx.y, t0 = blockIdx.x*32, tid = threadIdx.x;
  for (int i = tid; i < 390; i += 256){
    int rr = i/10, d = i - (i/10)*10;
    int t = t0 - 3 + rr;
    xs[rr][d] = (t >= 0 && t < TT) ? x[((size_t)b*TT + t)*10 + d] : 0.f;
  }
  __syncthreads();
  int co = tid & 127, th = tid >> 7;
  float wr[80];
  #pragma unroll
  for (int i = 0; i < 20; ++i) ((float4*)wr)[i] = ((const float4*)(w + co*80))[i];
  float acc[16];
  float bz = bias[co];
  #pragma unroll
  for (int i = 0; i < 16; ++i) acc[i] = bz;
  #pragma unroll
  for (int ci = 0; ci < 10; ++ci){
    float xr[23];
    #pragma unroll
    for (int i = 0; i < 23; ++i) xr[i] = xs[th*16 + i][ci];
    #pragma unroll
    for (int k = 0; k < 8; ++k){
      float wv = wr[ci*8 + k];
      #pragma unroll
      for (int i = 0; i < 16; ++i) acc[i] += wv*xr[i + k];
    }
  }
  #pragma unroll
  for (int i = 0; i < 16; ++i) outb[co][th*16 + i] = acc[i];
  __syncthreads();
  for (int i = tid; i < 4096; i += 256){
    int c2 = i >> 5, tt = i & 31;
    int t = t0 + tt;
    if (t < TT) h1[((size_t)b*128 + c2)*TT + t] = outb[c2][tt];
  }
}

template<int C>
__global__ void k_bnstats(const float* __restrict__ h, float* __restrict__ mean, float* __restrict__ rstd){
  int c = blockIdx.x, tid = threadIdx.x;
  double s1 = 0.0, s2 = 0.0;
  for (int n = tid; n < BB*TT; n += 256){
    int b = n/TT, t = n - b*TT;
    double v = (double)h[((size_t)b*C + c)*TT + t];
    s1 += v; s2 += v*v;
  }
  for (int o = 32; o > 0; o >>= 1){ s1 += __shfl_down(s1, o); s2 += __shfl_down(s2, o); }
  __shared__ double sh1[4], sh2[4];
  int wv = tid >> 6, ln = tid & 63;
  if (ln == 0){ sh1[wv] = s1; sh2[wv] = s2; }
  __syncthreads();
  if (tid == 0){
    double a = sh1[0]+sh1[1]+sh1[2]+sh1[3];
    double q = sh2[0]+sh2[1]+sh2[2]+sh2[3];
    double m = a/(double)(BB*TT);
    double v = q/(double)(BB*TT) - m*m;
    mean[c] = (float)m;
    rstd[c] = (float)(1.0/sqrt(v + 1e-5));
  }
}

// ---------------- conv2 via MFMA (hi/lo bf16 split) ----------------
// block: 256 thr / 4 waves; wave wv -> t-sub 16; co-block 64 (4 asub); K = 4 ci-chunks x 5 k.
__global__ __launch_bounds__(256) void k_conv2m(const float* __restrict__ h1,
    const unsigned short* __restrict__ wh, const unsigned short* __restrict__ wl,
    const float* __restrict__ bias, const float* __restrict__ g1, const float* __restrict__ b1,
    const float* __restrict__ mean1, const float* __restrict__ rstd1, float* __restrict__ h2){
  __shared__ __align__(16) unsigned short xh[68*128];
  __shared__ __align__(16) unsigned short xl[68*128];
  int tb = blockIdx.x, cb = blockIdx.y, b = blockIdx.z;
  int t0 = tb*64, tid = threadIdx.x;
  int lane = tid & 63, wv = tid >> 6;
  int l15 = lane & 15, sub = lane >> 4;

  for (int ci = wv; ci < 128; ci += 4){
    float m = mean1[ci], rs = rstd1[ci], g = g1[ci], bb = b1[ci];
    const float* src = h1 + ((size_t)b*128 + ci)*TT;
    for (int rr = lane; rr < 68; rr += 64){
      int t = t0 - 2 + rr;
      float v = 0.f;
      if (t >= 0 && t < TT) v = fmaxf(g*(src[t]-m)*rs + bb, 0.f);
      unsigned short hh, ll; fsplit(v, hh, ll);
      int off = rr*256 + ((ci*2) ^ ((rr&15)<<4));
      *(unsigned short*)((char*)xh + off) = hh;
      *(unsigned short*)((char*)xl + off) = ll;
    }
  }
  __syncthreads();

  f32x4 acc0 = {0.f,0.f,0.f,0.f}, acc1 = acc0, acc2 = acc0, acc3 = acc0;
  #pragma unroll
  for (int c = 0; c < 4; ++c){
    #pragma unroll
    for (int k = 0; k < 5; ++k){
      int rr = wv*16 + l15 + k;
      int off = rr*256 + ((c*64 + sub*16) ^ ((rr&15)<<4));
      bf16x8 bh = *(const bf16x8*)((const char*)xh + off);
      bf16x8 bl = *(const bf16x8*)((const char*)xl + off);
      size_t wb = ((size_t)((c*5 + k)*4 + sub)*256 + cb*64 + l15)*8;
      bf16x8 ah0 = *(const bf16x8*)(wh + wb);
      bf16x8 al0 = *(const bf16x8*)(wl + wb);
      bf16x8 ah1 = *(const bf16x8*)(wh + wb + 128);
      bf16x8 al1 = *(const bf16x8*)(wl + wb + 128);
      bf16x8 ah2 = *(const bf16x8*)(wh + wb + 256);
      bf16x8 al2 = *(const bf16x8*)(wl + wb + 256);
      bf16x8 ah3 = *(const bf16x8*)(wh + wb + 384);
      bf16x8 al3 = *(const bf16x8*)(wl + wb + 384);
      acc0 = mfma_bf16(ah0, bh, acc0); acc0 = mfma_bf16(al0, bh, acc0); acc0 = mfma_bf16(ah0, bl, acc0);
      acc1 = mfma_bf16(ah1, bh, acc1); acc1 = mfma_bf16(al1, bh, acc1); acc1 = mfma_bf16(ah1, bl, acc1);
      acc2 = mfma_bf16(ah2, bh, acc2); acc2 = mfma_bf16(al2, bh, acc2); acc2 = mfma_bf16(ah2, bl, acc2);
      acc3 = mfma_bf16(ah3, bh, acc3); acc3 = mfma_bf16(al3, bh, acc3); acc3 = mfma_bf16(ah3, bl, acc3);
    }
  }

  int colt = t0 + wv*16 + l15;
  if (colt < TT){
    #pragma unroll
    for (int r = 0; r < 4; ++r){
      int co0 = cb*64 + sub*4 + r;
      h2[((size_t)b*256 + co0      )*TT + colt] = acc0[r] + bias[co0];
      h2[((size_t)b*256 + co0 + 16 )*TT + colt] = acc1[r] + bias[co0 + 16];
      h2[((size_t)b*256 + co0 + 32 )*TT + colt] = acc2[r] + bias[co0 + 32];
      h2[((size_t)b*256 + co0 + 48 )*TT + colt] = acc3[r] + bias[co0 + 48];
    }
  }
}

// ---------------- conv3 via MFMA ----------------
// block: 128 thr / 2 waves; wave wv -> t-sub 32 (2 jt tiles); co-block 64; K = 8 chunks x 3 k.
__global__ __launch_bounds__(128) void k_conv3m(const float* __restrict__ h2,
    const unsigned short* __restrict__ wh, const unsigned short* __restrict__ wl,
    const float* __restrict__ bias, const float* __restrict__ g2, const float* __restrict__ b2,
    const float* __restrict__ mean2, const float* __restrict__ rstd2, float* __restrict__ h3){
  __shared__ __align__(16) unsigned short xh[68*256];
  __shared__ __align__(16) unsigned short xl[68*256];
  int tb = blockIdx.x, cb = blockIdx.y, b = blockIdx.z;
  int t0 = tb*64, tid = threadIdx.x;
  int lane = tid & 63, wv = tid >> 6;
  int l15 = lane & 15, sub = lane >> 4;

  for (int ci = wv; ci < 256; ci += 2){
    float m = mean2[ci], rs = rstd2[ci], g = g2[ci], bb = b2[ci];
    const float* src = h2 + ((size_t)b*256 + ci)*TT;
    for (int rr = lane; rr < 66; rr += 64){
      int t = t0 - 1 + rr;
      float v = 0.f;
      if (t >= 0 && t < TT) v = fmaxf(g*(src[t]-m)*rs + bb, 0.f);
      unsigned short hh, ll; fsplit(v, hh, ll);
      int off = rr*512 + ((ci*2) ^ ((rr&15)<<4));
      *(unsigned short*)((char*)xh + off) = hh;
      *(unsigned short*)((char*)xl + off) = ll;
    }
  }
  __syncthreads();

  f32x4 acc[4][2];
  #pragma unroll
  for (int a = 0; a < 4; ++a)
    #pragma unroll
    for (int j = 0; j < 2; ++j) acc[a][j] = (f32x4){0.f,0.f,0.f,0.f};

  #pragma unroll
  for (int c = 0; c < 8; ++c){
    #pragma unroll
    for (int k = 0; k < 3; ++k){
      bf16x8 bh[2], bl[2];
      #pragma unroll
      for (int j = 0; j < 2; ++j){
        int rr = wv*32 + j*16 + l15 + k;
        int off = rr*512 + ((c*64 + sub*16) ^ ((rr&15)<<4));
        bh[j] = *(const bf16x8*)((const char*)xh + off);
        bl[j] = *(const bf16x8*)((const char*)xl + off);
      }
      size_t wb = ((size_t)((c*3 + k)*4 + sub)*128 + cb*64 + l15)*8;
      #pragma unroll
      for (int a = 0; a < 4; ++a){
        bf16x8 ah = *(const bf16x8*)(wh + wb + a*128);
        bf16x8 al = *(const bf16x8*)(wl + wb + a*128);
        #pragma unroll
        for (int j = 0; j < 2; ++j){
          acc[a][j] = mfma_bf16(ah, bh[j], acc[a][j]);
          acc[a][j] = mfma_bf16(al, bh[j], acc[a][j]);
          acc[a][j] = mfma_bf16(ah, bl[j], acc[a][j]);
        }
      }
    }
  }

  #pragma unroll
  for (int j = 0; j < 2; ++j){
    int colt = t0 + wv*32 + j*16 + l15;
    if (colt < TT){
      #pragma unroll
      for (int a = 0; a < 4; ++a){
        #pragma unroll
        for (int r = 0; r < 4; ++r){
          int co = cb*64 + a*16 + sub*4 + r;
          h3[((size_t)b*128 + co)*TT + colt] = acc[a][j][r] + bias[co];
        }
      }
    }
  }
}

__global__ void k_gap(const float* __restrict__ h3, const float* __restrict__ g3, const float* __restrict__ b3,
                      const float* __restrict__ mean3, const float* __restrict__ rstd3, float* __restrict__ gap){
  int c = blockIdx.x, b = blockIdx.y, tid = threadIdx.x; // 64
  const float* row = h3 + ((size_t)b*128 + c)*TT;
  float m = mean3[c], r = rstd3[c], g = g3[c], bb = b3[c];
  float s = 0.f;
  for (int t = tid; t < TT; t += 64) s += fmaxf(g*(row[t]-m)*r + bb, 0.f);
  for (int o = 32; o > 0; o >>= 1) s += __shfl_down(s, o);
  if (tid == 0) gap[b*128 + c] = s/406.f;
}

__global__ void k_feat(const float* __restrict__ gap, const float* __restrict__ fw,
                       const float* __restrict__ fb, float* __restrict__ feat){
  int id = blockIdx.x*256 + threadIdx.x;
  if (id >= BB*128) return;
  int b = id >> 7, f = id & 127;
  float acc = fb[f];
  const float* gr = gap + b*128;
  for (int c = 0; c < 128; ++c) acc += gr[c]*fw[c*128 + f];
  feat[id] = acc;
}

__global__ void k_trans(const float* __restrict__ feat, const float* __restrict__ tw,
                        const float* __restrict__ tb, float* __restrict__ tmap2){
  int id = blockIdx.x*256 + threadIdx.x;
  int b = id/3072; int rem = id - b*3072; int k = rem >> 8; int o = rem & 255;
  float acc = tb[k*256 + o];
  const float* fr = feat + b*128;
  const float* wr = tw + ((size_t)k*128)*256 + o;
  for (int f = 0; f < 128; ++f) acc += fr[f]*wr[f*256];
  float val = tanhf(acc)*5.f;
  int p = o & 127, j = 2*k + (o >> 7);
  tmap2[((size_t)b*128 + p)*24 + j] = val;
}

__global__ void k_offscale(const float* __restrict__ feat, const float* __restrict__ ow,
                           const float* __restrict__ ob, const float* __restrict__ sw,
                           const float* __restrict__ sb, float* __restrict__ offv, float* __restrict__ scv){
  int id = blockIdx.x*256 + threadIdx.x;
  if (id >= BB*1280) return;
  int b = id/1280, o = id - b*1280;
  const float* fr = feat + b*128;
  float a1 = ob[o], a2 = sb[o];
  for (int f = 0; f < 128; ++f){
    float fv = fr[f];
    a1 += fv*ow[f*1280 + o];
    a2 += fv*sw[f*1280 + o];
  }
  offv[id] = tanhf(a1);
  scv[id]  = tanhf(a2)*0.75f + 1.25f;
}

__global__ __launch_bounds__(128) void k_smooth(const float* __restrict__ x, const int* __restrict__ mask,
    const float* __restrict__ gwt, float* __restrict__ out_inps, float* __restrict__ out_ms,
    float* __restrict__ inpT){
  int b = blockIdx.x, tid = threadIdx.x;
  __shared__ float xs[TT*DD];
  __shared__ float ms[TT];
  __shared__ float gw[TT];
  for (int i = tid; i < TT*DD; i += 128) xs[i] = x[(size_t)b*TT*DD + i];
  for (int i = tid; i < TT; i += 128){ ms[i] = (float)mask[b*TT + i]; gw[i] = gwt[i]; }
  __syncthreads();
  if (tid >= 102) return;
  int t = blockIdx.y*102 + tid;
  if (t >= TT) return;
  float a[10];
  #pragma unroll
  for (int d = 0; d < 10; ++d) a[d] = 0.f;
  float msum = 0.f;
  for (int i = 0; i < TT; ++i){
    float w = gw[(t > i) ? (t - i) : (i - t)];
    msum += w*ms[i];
    #pragma unroll
    for (int d = 0; d < 10; ++d) a[d] += w*xs[i*10 + d];
  }
  out_ms[b*TT + t] = msum;
  float den = (msum == 0.f) ? 1.f : msum;
  #pragma unroll
  for (int d = 0; d < 10; ++d){
    float v = a[d]/den;
    out_inps[((size_t)b*TT + t)*10 + d] = v;
    inpT[(size_t)b*TT*DD + (size_t)d*TT + t] = v;
  }
}

__global__ __launch_bounds__(64) void k_dist(const float* __restrict__ wsf, const float* __restrict__ proto,
                       const float* __restrict__ inpT, const float* __restrict__ msf,
                       const float* __restrict__ offv, const float* __restrict__ scv,
                       float* __restrict__ dist){
  int p = blockIdx.x, b = blockIdx.y, tid = threadIdx.x;
  __shared__ float pr[TT*DD];
  for (int i = tid; i < TT*DD; i += 64) pr[i] = proto[(size_t)p*TT*DD + i];
  const float* M24 = wsf + OFF_M24T;
  const float* by  = wsf + OFF_BY;
  const float* tm  = wsf + OFF_TMAP + ((size_t)b*128 + p)*24;
  float tmr[24];
  #pragma unroll
  for (int j = 0; j < 24; ++j) tmr[j] = tm[j];
  float ofr[10], scr[10];
  #pragma unroll
  for (int d = 0; d < 10; ++d){
    ofr[d] = offv[((size_t)b*128 + p)*10 + d];
    scr[d] = scv [((size_t)b*128 + p)*10 + d];
  }
  __syncthreads();
  float acc = 0.f;
  for (int t = tid; t < TT; t += 64){
    float y = by[t];
    #pragma unroll
    for (int j = 0; j < 24; ++j) y += M24[j*TT + t]*tmr[j];
    float pos = (y + 1.f)*0.5f*405.f;
    pos = fminf(fmaxf(pos, 0.f), 405.f);
    int i0 = (int)pos;
    float w = pos - (float)i0;
    int i1 = min(i0 + 1, 405);
    const float* p0 = pr + i0*10;
    const float* p1 = pr + i1*10;
    float s = 0.f;
    #pragma unroll
    for (int d = 0; d < 10; ++d){
      float val = (p0[d]*(1.f - w) + p1[d]*w + ofr[d])*scr[d];
      float df = inpT[(size_t)b*TT*DD + (size_t)d*TT + t] - val;
      s += df*df;
    }
    acc += msf[b*TT + t]*s;
  }
  for (int o = 32; o > 0; o >>= 1) acc += __shfl_down(acc, o);
  if (tid == 0) dist[b*128 + p] = acc;
}

__global__ void k_argmin(const float* __restrict__ dist, const int* __restrict__ label,
                         int* __restrict__ idxws, float* __restrict__ out3, float* __restrict__ out4){
  int b = threadIdx.x;
  if (b >= BB) return;
  const float* dr = dist + b*128;
  float best = dr[0]; int bi = 0;
  for (int p = 1; p < 128; ++p){
    float v = dr[p];
    if (v < best){ best = v; bi = p; }
  }
  idxws[b] = bi;
  out3[b] = (float)bi;
  out4[b] = (float)label[b];
}

__global__ void k_out(const float* __restrict__ wsf, const float* __restrict__ proto,
                      const float* __restrict__ offv, const float* __restrict__ scv,
                      const int* __restrict__ idxws, float* __restrict__ out0){
  int b = blockIdx.y;
  int t = blockIdx.x*64 + threadIdx.x;
  if (t >= TT) return;
  int p = idxws[b];
  const float* tm = wsf + OFF_TMAP + ((size_t)b*128 + p)*24;
  const float* M24 = wsf + OFF_M24T;
  float y = wsf[OFF_BY + t];
  #pragma unroll
  for (int j = 0; j < 24; ++j) y += M24[j*TT + t]*tm[j];
  float pos = (y + 1.f)*0.5f*405.f;
  pos = fminf(fmaxf(pos, 0.f), 405.f);
  int i0 = (int)pos;
  float w = pos - (float)i0;
  int i1 = min(i0 + 1, 405);
  const float* p0 = proto + ((size_t)p*TT + i0)*10;
  const float* p1 = proto + ((size_t)p*TT + i1)*10;
  #pragma unroll
  for (int d = 0; d < 10; ++d){
    float val = (p0[d]*(1.f - w) + p1[d]*w + offv[((size_t)b*128 + p)*10 + d])*scv[((size_t)b*128 + p)*10 + d];
    out0[((size_t)b*TT + t)*10 + d] = val;
  }
}

// ---------------- launch ----------------
extern "C" void kernel_launch(void* const* d_in, const int* in_sizes, int n_in,
                              void* d_out, int out_size, void* d_ws, size_t ws_size,
                              hipStream_t stream){
  const float* input_seq = (const float*)d_in[0];
  const int*   label     = (const int*)  d_in[1];
  const int*   mask      = (const int*)  d_in[2];
  const float* proto     = (const float*)d_in[3];
  const float* c1w = (const float*)d_in[4];  const float* c1b = (const float*)d_in[5];
  const float* g1  = (const float*)d_in[6];  const float* b1  = (const float*)d_in[7];
  const float* c2w = (const float*)d_in[8];  const float* c2b = (const float*)d_in[9];
  const float* g2  = (const float*)d_in[10]; const float* b2  = (const float*)d_in[11];
  const float* c3w = (const float*)d_in[12]; const float* c3b = (const float*)d_in[13];
  const float* g3  = (const float*)d_in[14]; const float* b3  = (const float*)d_in[15];
  const float* fw  = (const float*)d_in[16]; const float* fb  = (const float*)d_in[17];
  const float* tw  = (const float*)d_in[18]; const float* tb  = (const float*)d_in[19];
  const float* ow  = (const float*)d_in[20]; const float* ob  = (const float*)d_in[21];
  const float* sw  = (const float*)d_in[22]; const float* sb  = (const float*)d_in[23];

  float* wsf = (float*)d_ws;
  float* out0 = (float*)d_out;             // (B,T,D) 259840
  float* out1 = out0 + 259840;             // inp_s   259840
  float* out2 = out0 + 519680;             // dist    8192
  float* out3 = out0 + 527872;             // indices 64
  float* out4 = out0 + 527936;             // label   64
  float* out5 = out0 + 528000;             // mask_s  25984

  float* h1 = wsf + OFF_H1;
  float* h2 = wsf + OFF_H2;
  float* h3 = h1;                          // h1 dead after conv2
  float* inpT = wsf + OFF_INPT;            // h2 dead after conv3
  unsigned short* wu = (unsigned short*)(wsf + OFF_TMAP);
  const unsigned short* wh2 = wu;
  const unsigned short* wl2 = wu + 163840;
  const unsigned short* wh3 = wu + 327680;
  const unsigned short* wl3 = wu + 327680 + 98304;

  k_tps_inv<<<dim3(1), dim3(256), 0, stream>>>(wsf);
  k_tps_rep<<<dim3(7), dim3(64), 0, stream>>>(wsf);
  k_wprep<<<dim3(1024), dim3(256), 0, stream>>>(c2w, c3w, wu);
  k_conv1<<<dim3(13,BB), 256, 0, stream>>>(input_seq, c1w, c1b, h1);
  k_bnstats<128><<<128, 256, 0, stream>>>(h1, wsf+OFF_MEAN1, wsf+OFF_RSTD1);
  k_conv2m<<<dim3(7,4,BB), 256, 0, stream>>>(h1, wh2, wl2, c2b, g1, b1, wsf+OFF_MEAN1, wsf+OFF_RSTD1, h2);
  k_bnstats<256><<<256, 256, 0, stream>>>(h2, wsf+OFF_MEAN2, wsf+OFF_RSTD2);
  k_conv3m<<<dim3(7,2,BB), 128, 0, stream>>>(h2, wh3, wl3, c3b, g2, b2, wsf+OFF_MEAN2, wsf+OFF_RSTD2, h3);
  k_bnstats<128><<<128, 256, 0, stream>>>(h3, wsf+OFF_MEAN3, wsf+OFF_RSTD3);
  k_gap<<<dim3(128,BB), 64, 0, stream>>>(h3, g3, b3, wsf+OFF_MEAN3, wsf+OFF_RSTD3, wsf+OFF_GAP);
  k_feat<<<32, 256, 0, stream>>>(wsf+OFF_GAP, fw, fb, wsf+OFF_FEAT);
  k_trans<<<768, 256, 0, stream>>>(wsf+OFF_FEAT, tw, tb, wsf+OFF_TMAP);
  k_offscale<<<320, 256, 0, stream>>>(wsf+OFF_FEAT, ow, ob, sw, sb, wsf+OFF_OFFV, wsf+OFF_SCV);
  k_smooth<<<dim3(BB,4), 128, 0, stream>>>(input_seq, mask, wsf+OFF_GW, out1, out5, inpT);
  k_dist<<<dim3(128,BB), 64, 0, stream>>>(wsf, proto, inpT, out5, wsf+OFF_OFFV, wsf+OFF_SCV, out2);
  k_argmin<<<1, 64, 0, stream>>>(out2, label, (int*)(wsf+OFF_IDX), out3, out4);
  k_out<<<dim3(7,BB), 64, 0, stream>>>(wsf, proto, wsf+OFF_OFFV, wsf+OFF_SCV, (int*)(wsf+OFF_IDX), out0);
}

// Round 12
// 469.914 us; speedup vs baseline: 2.2866x; 1.3689x over previous
//
#include <hip/hip_runtime.h>
#include <math.h>

#define TT 406
#define DD 10
#define PP 128
#define FF 128
#define BB 64

using bf16x8 = __attribute__((ext_vector_type(8))) short;
using f32x4  = __attribute__((ext_vector_type(4))) float;

// ---------------- workspace layout (float offsets) ----------------
constexpr size_t OFF_GW    = 0;                       // 406
constexpr size_t OFF_M24T  = 448;                     // [24][406] = 9744 (transposed)
constexpr size_t OFF_BY    = 10240;                   // 406
constexpr size_t OFF_MEAN1 = 10688;                   // 128
constexpr size_t OFF_RSTD1 = 10816;                   // 128
constexpr size_t OFF_MEAN2 = 10944;                   // 256
constexpr size_t OFF_RSTD2 = 11200;                   // 256
constexpr size_t OFF_MEAN3 = 11456;                   // 128
constexpr size_t OFF_RSTD3 = 11584;                   // 128
constexpr size_t OFF_GAP   = 11712;                   // 8192
constexpr size_t OFF_INVF  = OFF_GAP;                 // 961 f32 (dead before k_gap)
constexpr size_t OFF_FEAT  = 19904;                   // 8192
constexpr size_t OFF_IDX   = 28096;                   // 64 (int)
constexpr size_t OFF_TMAP  = 28160;                   // 196608 (written by k_trans, late)
// bf16 weight planes (ushort units, based at OFF_TMAP): dead before k_trans/k_offscale write
//   WH2: 163840 ush | WL2: 163840 | WH3: 98304 | WL3: 98304  => 262144 floats [28160,290304)
constexpr size_t OFF_OFFV  = 224768;                  // 81920 (written by k_offscale, late)
constexpr size_t OFF_SCV   = 306688;                  // 81920
constexpr size_t OFF_H1    = 388608;                  // 64*128*406 = 3325952 (aliased as h3)
constexpr size_t OFF_H2    = OFF_H1 + (size_t)BB*128*TT; // 6651904
constexpr size_t OFF_INPT  = OFF_H2;                  // 259840: inpT[b][d][t] (h2 dead after conv3)
// total = 10,366,464 floats = 41.5 MB (unchanged footprint)

__device__ __forceinline__ f32x4 mfma_bf16(bf16x8 a, bf16x8 b, f32x4 c){
  return __builtin_amdgcn_mfma_f32_16x16x32_bf16(a, b, c, 0, 0, 0);
}

// split f32 -> bf16 hi (truncate) + bf16 lo (RNE of remainder): hi+lo ~ 24-bit mantissa
__device__ __forceinline__ void fsplit(float x, unsigned short &h, unsigned short &l){
  union { float f; unsigned int u; } a; a.f = x;
  unsigned short hh = (unsigned short)(a.u >> 16);
  union { float f; unsigned int u; } hf; hf.u = ((unsigned int)hh) << 16;
  float r = x - hf.f;
  union { float f; unsigned int u; } bb; bb.f = r;
  unsigned int u = bb.u;
  unsigned int rnd = u + 0x7FFFu + ((u >> 16) & 1u);
  h = hh; l = (unsigned short)(rnd >> 16);
}

// ---------------- TPS constant helpers ----------------
__device__ __forceinline__ double tcpx(int n){ return -1.0 + 2.0*(double)(n>>1)/13.0; }
__device__ __forceinline__ double tcpy(int n){ return (n&1) ? 1.0 : -1.0; }
__device__ __forceinline__ double Ufun(double d2){ return d2 > 0.0 ? 0.5*d2*log(d2) : 0.0; }

__global__ __launch_bounds__(256) void k_tps_inv(float* __restrict__ ws){
  __shared__ double aug[31][62];
  __shared__ double fac[31];
  __shared__ int pivrow;
  int tid = threadIdx.x;

  for (int i = tid; i < TT; i += 256){
    float d = (float)i;
    ws[OFF_GW + i] = expf(-(d*d)/98.f);
  }

  for (int idx = tid; idx < 31*62; idx += 256){
    int r = idx/62, c = idx - (idx/62)*62;
    double v = 0.0;
    if (c < 31){
      if (r < 28 && c < 28){
        double dx = tcpx(r)-tcpx(c), dy = tcpy(r)-tcpy(c);
        v = Ufun(dx*dx + dy*dy);
      } else if (r < 28 && c == 28) v = 1.0;
      else if (r == 28 && c < 28)  v = 1.0;
      else if (r < 28 && c == 29)  v = tcpx(r);
      else if (r < 28 && c == 30)  v = tcpy(r);
      else if (r == 29 && c < 28)  v = tcpx(c);
      else if (r == 30 && c < 28)  v = tcpy(c);
      else v = 0.0;
    } else {
      v = ((c-31) == r) ? 1.0 : 0.0;
    }
    aug[r][c] = v;
  }
  __syncthreads();

  for (int k = 0; k < 31; ++k){
    if (tid < 64){
      double v = (tid >= k && tid < 31) ? fabs(aug[tid][k]) : -1.0;
      int idx = tid;
      for (int o = 32; o > 0; o >>= 1){
        double ov = __shfl_down(v, o);
        int oi = __shfl_down(idx, o);
        if (ov > v){ v = ov; idx = oi; }
      }
      if (tid == 0) pivrow = idx;
    }
    __syncthreads();
    int pr = pivrow;
    if (pr != k){
      for (int c = tid; c < 62; c += 256){
        double t = aug[k][c]; aug[k][c] = aug[pr][c]; aug[pr][c] = t;
      }
    }
    __syncthreads();
    double pk = aug[k][k];
    __syncthreads();
    double pinv = 1.0/pk;
    for (int c = tid; c < 62; c += 256) aug[k][c] *= pinv;
    __syncthreads();
    for (int r = tid; r < 31; r += 256) fac[r] = aug[r][k];
    __syncthreads();
    for (int idx = tid; idx < 31*62; idx += 256){
      int r = idx/62, c = idx - (idx/62)*62;
      if (r != k) aug[r][c] -= fac[r]*aug[k][c];
    }
    __syncthreads();
  }

  for (int idx = tid; idx < 31*31; idx += 256){
    int n = idx/31, m = idx - (idx/31)*31;
    ws[OFF_INVF + (size_t)n*31 + m] = (float)aug[n][31+m];
  }
}

__global__ void k_tps_rep(float* __restrict__ ws){
  __shared__ float sinv[31*31];
  int tid = threadIdx.x;
  for (int i = tid; i < 31*31; i += 64) sinv[i] = ws[OFF_INVF + i];
  __syncthreads();
  int t = blockIdx.x*64 + tid;
  if (t >= TT) return;
  float yt = -1.f + 2.f*(float)t/405.f;
  float rep[31];
  #pragma unroll
  for (int n = 0; n < 28; ++n){
    float dx = -1.f - (-1.f + 2.f*(float)(n>>1)/13.f);
    float dy = yt - ((n&1) ? 1.f : -1.f);
    float d2 = dx*dx + dy*dy;
    rep[n] = (d2 > 0.f) ? 0.5f*d2*logf(d2) : 0.f;
  }
  rep[28] = 1.f; rep[29] = -1.f; rep[30] = yt;
  float Mm[28];
  #pragma unroll
  for (int m = 0; m < 28; ++m){
    float s = 0.f;
    #pragma unroll
    for (int n = 0; n < 31; ++n) s += rep[n]*sinv[n*31 + m];
    Mm[m] = s;
  }
  float base = 0.f;
  #pragma unroll
  for (int m = 0; m < 28; ++m) base += Mm[m]*((m&1) ? 1.f : -1.f);
  ws[OFF_BY + t] = base;
  #pragma unroll
  for (int j = 0; j < 24; ++j) ws[OFF_M24T + (size_t)j*TT + t] = Mm[j+2];
}

// pack conv2/conv3 weights into MFMA A-fragment order, bf16 hi/lo planes.
// WH2[c(4)][k(5)][sub(4)][co(256)][b(8)], ci = c*32+sub*8+b ; same scheme for conv3.
__global__ void k_wprep(const float* __restrict__ w2, const float* __restrict__ w3,
                        unsigned short* __restrict__ wu){
  int idx = blockIdx.x*256 + threadIdx.x;
  if (idx >= 262144) return;
  float x; int dh, dl;
  if (idx < 163840){
    int bb = idx & 7, r = idx >> 3;
    int co = r & 255; r >>= 8;
    int sub = r & 3; r >>= 2;           // r = c*5+k
    int k = r % 5, c = r / 5;
    int ci = c*32 + sub*8 + bb;
    x = w2[co*640 + ci*5 + k];
    dh = idx; dl = idx + 163840;
  } else {
    int j = idx - 163840;
    int bb = j & 7, r = j >> 3;
    int co = r & 127; r >>= 7;
    int sub = r & 3; r >>= 2;           // r = c*3+k
    int k = r % 3, c = r / 3;
    int ci = c*32 + sub*8 + bb;
    x = w3[co*768 + ci*3 + k];
    dh = 327680 + j; dl = 327680 + 98304 + j;
  }
  unsigned short h, l; fsplit(x, h, l);
  wu[dh] = h; wu[dl] = l;
}

// ---------------- conv1: weights in regs, x in LDS, transposed store ----------------
__global__ __launch_bounds__(256) void k_conv1(const float* __restrict__ x, const float* __restrict__ w,
                        const float* __restrict__ bias, float* __restrict__ h1){
  __shared__ float xs[39][10];
  __shared__ float outb[128][33];
  int b = blockIdx.y, t0 = blockIdx.x*32, tid = threadIdx.x;
  for (int i = tid; i < 390; i += 256){
    int rr = i/10, d = i - (i/10)*10;
    int t = t0 - 3 + rr;
    xs[rr][d] = (t >= 0 && t < TT) ? x[((size_t)b*TT + t)*10 + d] : 0.f;
  }
  __syncthreads();
  int co = tid & 127, th = tid >> 7;
  float wr[80];
  #pragma unroll
  for (int i = 0; i < 20; ++i) ((float4*)wr)[i] = ((const float4*)(w + co*80))[i];
  float acc[16];
  float bz = bias[co];
  #pragma unroll
  for (int i = 0; i < 16; ++i) acc[i] = bz;
  #pragma unroll
  for (int ci = 0; ci < 10; ++ci){
    float xr[23];
    #pragma unroll
    for (int i = 0; i < 23; ++i) xr[i] = xs[th*16 + i][ci];
    #pragma unroll
    for (int k = 0; k < 8; ++k){
      float wv = wr[ci*8 + k];
      #pragma unroll
      for (int i = 0; i < 16; ++i) acc[i] += wv*xr[i + k];
    }
  }
  #pragma unroll
  for (int i = 0; i < 16; ++i) outb[co][th*16 + i] = acc[i];
  __syncthreads();
  for (int i = tid; i < 4096; i += 256){
    int c2 = i >> 5, tt = i & 31;
    int t = t0 + tt;
    if (t < TT) h1[((size_t)b*128 + c2)*TT + t] = outb[c2][tt];
  }
}

template<int C>
__global__ void k_bnstats(const float* __restrict__ h, float* __restrict__ mean, float* __restrict__ rstd){
  int c = blockIdx.x, tid = threadIdx.x;
  double s1 = 0.0, s2 = 0.0;
  for (int n = tid; n < BB*TT; n += 256){
    int b = n/TT, t = n - b*TT;
    double v = (double)h[((size_t)b*C + c)*TT + t];
    s1 += v; s2 += v*v;
  }
  for (int o = 32; o > 0; o >>= 1){ s1 += __shfl_down(s1, o); s2 += __shfl_down(s2, o); }
  __shared__ double sh1[4], sh2[4];
  int wv = tid >> 6, ln = tid & 63;
  if (ln == 0){ sh1[wv] = s1; sh2[wv] = s2; }
  __syncthreads();
  if (tid == 0){
    double a = sh1[0]+sh1[1]+sh1[2]+sh1[3];
    double q = sh2[0]+sh2[1]+sh2[2]+sh2[3];
    double m = a/(double)(BB*TT);
    double v = q/(double)(BB*TT) - m*m;
    mean[c] = (float)m;
    rstd[c] = (float)(1.0/sqrt(v + 1e-5));
  }
}

// ---------------- conv2 via MFMA (merged co, packed-b32 staging, 4 waves) ----------------
// grid (7, B). block 256 thr / 4 waves. wave w: co 64 = w*64 + a*16, t full 64 (j 0..3).
__global__ __launch_bounds__(256, 3) void k_conv2m(const float* __restrict__ h1,
    const unsigned short* __restrict__ wh, const unsigned short* __restrict__ wl,
    const float* __restrict__ bias, const float* __restrict__ g1, const float* __restrict__ b1,
    const float* __restrict__ mean1, const float* __restrict__ rstd1, float* __restrict__ h2){
  __shared__ __align__(16) unsigned short xh[68*128];
  __shared__ __align__(16) unsigned short xl[68*128];
  int tb = blockIdx.x, b = blockIdx.y;
  int t0 = tb*64, tid = threadIdx.x;
  int lane = tid & 63, wv = tid >> 6;
  int l15 = lane & 15, sub = lane >> 4;

  // staging: 80 tiles of (16rr x 4ci-pair); lane -> (rr=l15, cipair=lane>>4).
  // write b32 (2 packed ushorts) at rr*256 + (ci*2 ^ ((rr&7)<<4)): 32 banks, 2-way = free.
  for (int it = wv*20; it < wv*20 + 20; ++it){
    int rb = it >> 4, cpb = it & 15;
    int rr = rb*16 + l15;
    if (rr < 68){
      int ci = (cpb*4 + sub)*2;
      int t = t0 - 2 + rr;
      float v0 = 0.f, v1 = 0.f;
      if (t >= 0 && t < TT){
        const float* s0 = h1 + ((size_t)b*128 + ci)*TT + t;
        v0 = fmaxf(g1[ci  ]*(s0[0 ] - mean1[ci  ])*rstd1[ci  ] + b1[ci  ], 0.f);
        v1 = fmaxf(g1[ci+1]*(s0[TT] - mean1[ci+1])*rstd1[ci+1] + b1[ci+1], 0.f);
      }
      unsigned short h0, l0, h1u, l1u;
      fsplit(v0, h0, l0); fsplit(v1, h1u, l1u);
      unsigned int hp = (unsigned int)h0 | ((unsigned int)h1u << 16);
      unsigned int lp = (unsigned int)l0 | ((unsigned int)l1u << 16);
      int off = rr*256 + ((ci*2) ^ ((rr&7)<<4));
      *(unsigned int*)((char*)xh + off) = hp;
      *(unsigned int*)((char*)xl + off) = lp;
    }
  }
  __syncthreads();

  f32x4 acc[4][4];
  #pragma unroll
  for (int a = 0; a < 4; ++a)
    #pragma unroll
    for (int j = 0; j < 4; ++j) acc[a][j] = (f32x4){0.f,0.f,0.f,0.f};

  int wvco = wv*64;
  #pragma unroll
  for (int c = 0; c < 4; ++c){
    #pragma unroll
    for (int k = 0; k < 5; ++k){
      bf16x8 bh[4], bl[4];
      #pragma unroll
      for (int j = 0; j < 4; ++j){
        int rr = j*16 + l15 + k;
        int off = rr*256 + ((c*64 + sub*16) ^ ((rr&7)<<4));
        bh[j] = *(const bf16x8*)((const char*)xh + off);
        bl[j] = *(const bf16x8*)((const char*)xl + off);
      }
      #pragma unroll
      for (int a = 0; a < 4; ++a){
        size_t wb = ((size_t)((c*5 + k)*4 + sub)*256 + wvco + a*16 + l15)*8;
        bf16x8 ah = *(const bf16x8*)(wh + wb);
        bf16x8 al = *(const bf16x8*)(wl + wb);
        #pragma unroll
        for (int j = 0; j < 4; ++j){
          acc[a][j] = mfma_bf16(ah, bh[j], acc[a][j]);
          acc[a][j] = mfma_bf16(al, bh[j], acc[a][j]);
          acc[a][j] = mfma_bf16(ah, bl[j], acc[a][j]);
        }
      }
    }
  }

  #pragma unroll
  for (int j = 0; j < 4; ++j){
    int colt = t0 + j*16 + l15;
    if (colt < TT){
      #pragma unroll
      for (int a = 0; a < 4; ++a){
        #pragma unroll
        for (int r = 0; r < 4; ++r){
          int co = wvco + a*16 + sub*4 + r;
          h2[((size_t)b*256 + co)*TT + colt] = acc[a][j][r] + bias[co];
        }
      }
    }
  }
}

// ---------------- conv3 via MFMA (merged co, 2 ci-chunks, 4 waves) ----------------
// grid (7, B). wave w: co-half (w&1)*64, t-half (w>>1)*32 (j 0..1).
__global__ __launch_bounds__(256, 3) void k_conv3m(const float* __restrict__ h2,
    const unsigned short* __restrict__ wh, const unsigned short* __restrict__ wl,
    const float* __restrict__ bias, const float* __restrict__ g2, const float* __restrict__ b2,
    const float* __restrict__ mean2, const float* __restrict__ rstd2, float* __restrict__ h3){
  __shared__ __align__(16) unsigned short xh[68*128];
  __shared__ __align__(16) unsigned short xl[68*128];
  int tb = blockIdx.x, b = blockIdx.y;
  int t0 = tb*64, tid = threadIdx.x;
  int lane = tid & 63, wv = tid >> 6;
  int l15 = lane & 15, sub = lane >> 4;
  int coh = (wv & 1)*64, th = wv >> 1;

  f32x4 acc[4][2];
  #pragma unroll
  for (int a = 0; a < 4; ++a)
    #pragma unroll
    for (int j = 0; j < 2; ++j) acc[a][j] = (f32x4){0.f,0.f,0.f,0.f};

  for (int chunk = 0; chunk < 2; ++chunk){
    if (chunk) __syncthreads();      // all waves done reading prev chunk
    for (int it = wv*20; it < wv*20 + 20; ++it){
      int rb = it >> 4, cpb = it & 15;
      int rr = rb*16 + l15;
      if (rr < 66){
        int ci = (cpb*4 + sub)*2;
        int cig = chunk*128 + ci;
        int t = t0 - 1 + rr;
        float v0 = 0.f, v1 = 0.f;
        if (t >= 0 && t < TT){
          const float* s0 = h2 + ((size_t)b*256 + cig)*TT + t;
          v0 = fmaxf(g2[cig  ]*(s0[0 ] - mean2[cig  ])*rstd2[cig  ] + b2[cig  ], 0.f);
          v1 = fmaxf(g2[cig+1]*(s0[TT] - mean2[cig+1])*rstd2[cig+1] + b2[cig+1], 0.f);
        }
        unsigned short h0, l0, h1u, l1u;
        fsplit(v0, h0, l0); fsplit(v1, h1u, l1u);
        unsigned int hp = (unsigned int)h0 | ((unsigned int)h1u << 16);
        unsigned int lp = (unsigned int)l0 | ((unsigned int)l1u << 16);
        int off = rr*256 + ((ci*2) ^ ((rr&7)<<4));
        *(unsigned int*)((char*)xh + off) = hp;
        *(unsigned int*)((char*)xl + off) = lp;
      }
    }
    __syncthreads();

    #pragma unroll
    for (int cl = 0; cl < 4; ++cl){
      int c = chunk*4 + cl;
      #pragma unroll
      for (int k = 0; k < 3; ++k){
        bf16x8 bh[2], bl[2];
        #pragma unroll
        for (int j = 0; j < 2; ++j){
          int rr = th*32 + j*16 + l15 + k;
          int off = rr*256 + ((cl*64 + sub*16) ^ ((rr&7)<<4));
          bh[j] = *(const bf16x8*)((const char*)xh + off);
          bl[j] = *(const bf16x8*)((const char*)xl + off);
        }
        #pragma unroll
        for (int a = 0; a < 4; ++a){
          size_t wb = ((size_t)((c*3 + k)*4 + sub)*128 + coh + a*16 + l15)*8;
          bf16x8 ah = *(const bf16x8*)(wh + wb);
          bf16x8 al = *(const bf16x8*)(wl + wb);
          #pragma unroll
          for (int j = 0; j < 2; ++j){
            acc[a][j] = mfma_bf16(ah, bh[j], acc[a][j]);
            acc[a][j] = mfma_bf16(al, bh[j], acc[a][j]);
            acc[a][j] = mfma_bf16(ah, bl[j], acc[a][j]);
          }
        }
      }
    }
  }

  #pragma unroll
  for (int j = 0; j < 2; ++j){
    int colt = t0 + th*32 + j*16 + l15;
    if (colt < TT){
      #pragma unroll
      for (int a = 0; a < 4; ++a){
        #pragma unroll
        for (int r = 0; r < 4; ++r){
          int co = coh + a*16 + sub*4 + r;
          h3[((size_t)b*128 + co)*TT + colt] = acc[a][j][r] + bias[co];
        }
      }
    }
  }
}

__global__ void k_gap(const float* __restrict__ h3, const float* __restrict__ g3, const float* __restrict__ b3,
                      const float* __restrict__ mean3, const float* __restrict__ rstd3, float* __restrict__ gap){
  int c = blockIdx.x, b = blockIdx.y, tid = threadIdx.x; // 64
  const float* row = h3 + ((size_t)b*128 + c)*TT;
  float m = mean3[c], r = rstd3[c], g = g3[c], bb = b3[c];
  float s = 0.f;
  for (int t = tid; t < TT; t += 64) s += fmaxf(g*(row[t]-m)*r + bb, 0.f);
  for (int o = 32; o > 0; o >>= 1) s += __shfl_down(s, o);
  if (tid == 0) gap[b*128 + c] = s/406.f;
}

__global__ void k_feat(const float* __restrict__ gap, const float* __restrict__ fw,
                       const float* __restrict__ fb, float* __restrict__ feat){
  int id = blockIdx.x*256 + threadIdx.x;
  if (id >= BB*128) return;
  int b = id >> 7, f = id & 127;
  float acc = fb[f];
  const float* gr = gap + b*128;
  for (int c = 0; c < 128; ++c) acc += gr[c]*fw[c*128 + f];
  feat[id] = acc;
}

__global__ void k_trans(const float* __restrict__ feat, const float* __restrict__ tw,
                        const float* __restrict__ tb, float* __restrict__ tmap2){
  int id = blockIdx.x*256 + threadIdx.x;
  int b = id/3072; int rem = id - b*3072; int k = rem >> 8; int o = rem & 255;
  float acc = tb[k*256 + o];
  const float* fr = feat + b*128;
  const float* wr = tw + ((size_t)k*128)*256 + o;
  for (int f = 0; f < 128; ++f) acc += fr[f]*wr[f*256];
  float val = tanhf(acc)*5.f;
  int p = o & 127, j = 2*k + (o >> 7);
  tmap2[((size_t)b*128 + p)*24 + j] = val;
}

__global__ void k_offscale(const float* __restrict__ feat, const float* __restrict__ ow,
                           const float* __restrict__ ob, const float* __restrict__ sw,
                           const float* __restrict__ sb, float* __restrict__ offv, float* __restrict__ scv){
  int id = blockIdx.x*256 + threadIdx.x;
  if (id >= BB*1280) return;
  int b = id/1280, o = id - b*1280;
  const float* fr = feat + b*128;
  float a1 = ob[o], a2 = sb[o];
  for (int f = 0; f < 128; ++f){
    float fv = fr[f];
    a1 += fv*ow[f*1280 + o];
    a2 += fv*sw[f*1280 + o];
  }
  offv[id] = tanhf(a1);
  scv[id]  = tanhf(a2)*0.75f + 1.25f;
}

__global__ __launch_bounds__(128) void k_smooth(const float* __restrict__ x, const int* __restrict__ mask,
    const float* __restrict__ gwt, float* __restrict__ out_inps, float* __restrict__ out_ms,
    float* __restrict__ inpT){
  int b = blockIdx.x, tid = threadIdx.x;
  __shared__ float xs[TT*DD];
  __shared__ float ms[TT];
  __shared__ float gw[TT];
  for (int i = tid; i < TT*DD; i += 128) xs[i] = x[(size_t)b*TT*DD + i];
  for (int i = tid; i < TT; i += 128){ ms[i] = (float)mask[b*TT + i]; gw[i] = gwt[i]; }
  __syncthreads();
  if (tid >= 102) return;
  int t = blockIdx.y*102 + tid;
  if (t >= TT) return;
  float a[10];
  #pragma unroll
  for (int d = 0; d < 10; ++d) a[d] = 0.f;
  float msum = 0.f;
  for (int i = 0; i < TT; ++i){
    float w = gw[(t > i) ? (t - i) : (i - t)];
    msum += w*ms[i];
    #pragma unroll
    for (int d = 0; d < 10; ++d) a[d] += w*xs[i*10 + d];
  }
  out_ms[b*TT + t] = msum;
  float den = (msum == 0.f) ? 1.f : msum;
  #pragma unroll
  for (int d = 0; d < 10; ++d){
    float v = a[d]/den;
    out_inps[((size_t)b*TT + t)*10 + d] = v;
    inpT[(size_t)b*TT*DD + (size_t)d*TT + t] = v;
  }
}

__global__ __launch_bounds__(64) void k_dist(const float* __restrict__ wsf, const float* __restrict__ proto,
                       const float* __restrict__ inpT, const float* __restrict__ msf,
                       const float* __restrict__ offv, const float* __restrict__ scv,
                       float* __restrict__ dist){
  int p = blockIdx.x, b = blockIdx.y, tid = threadIdx.x;
  __shared__ float pr[TT*DD];
  for (int i = tid; i < TT*DD; i += 64) pr[i] = proto[(size_t)p*TT*DD + i];
  const float* M24 = wsf + OFF_M24T;
  const float* by  = wsf + OFF_BY;
  const float* tm  = wsf + OFF_TMAP + ((size_t)b*128 + p)*24;
  float tmr[24];
  #pragma unroll
  for (int j = 0; j < 24; ++j) tmr[j] = tm[j];
  float ofr[10], scr[10];
  #pragma unroll
  for (int d = 0; d < 10; ++d){
    ofr[d] = offv[((size_t)b*128 + p)*10 + d];
    scr[d] = scv [((size_t)b*128 + p)*10 + d];
  }
  __syncthreads();
  float acc = 0.f;
  for (int t = tid; t < TT; t += 64){
    float y = by[t];
    #pragma unroll
    for (int j = 0; j < 24; ++j) y += M24[j*TT + t]*tmr[j];
    float pos = (y + 1.f)*0.5f*405.f;
    pos = fminf(fmaxf(pos, 0.f), 405.f);
    int i0 = (int)pos;
    float w = pos - (float)i0;
    int i1 = min(i0 + 1, 405);
    const float* p0 = pr + i0*10;
    const float* p1 = pr + i1*10;
    float s = 0.f;
    #pragma unroll
    for (int d = 0; d < 10; ++d){
      float val = (p0[d]*(1.f - w) + p1[d]*w + ofr[d])*scr[d];
      float df = inpT[(size_t)b*TT*DD + (size_t)d*TT + t] - val;
      s += df*df;
    }
    acc += msf[b*TT + t]*s;
  }
  for (int o = 32; o > 0; o >>= 1) acc += __shfl_down(acc, o);
  if (tid == 0) dist[b*128 + p] = acc;
}

__global__ void k_argmin(const float* __restrict__ dist, const int* __restrict__ label,
                         int* __restrict__ idxws, float* __restrict__ out3, float* __restrict__ out4){
  int b = threadIdx.x;
  if (b >= BB) return;
  const float* dr = dist + b*128;
  float best = dr[0]; int bi = 0;
  for (int p = 1; p < 128; ++p){
    float v = dr[p];
    if (v < best){ best = v; bi = p; }
  }
  idxws[b] = bi;
  out3[b] = (float)bi;
  out4[b] = (float)label[b];
}

__global__ void k_out(const float* __restrict__ wsf, const float* __restrict__ proto,
                      const float* __restrict__ offv, const float* __restrict__ scv,
                      const int* __restrict__ idxws, float* __restrict__ out0){
  int b = blockIdx.y;
  int t = blockIdx.x*64 + threadIdx.x;
  if (t >= TT) return;
  int p = idxws[b];
  const float* tm = wsf + OFF_TMAP + ((size_t)b*128 + p)*24;
  const float* M24 = wsf + OFF_M24T;
  float y = wsf[OFF_BY + t];
  #pragma unroll
  for (int j = 0; j < 24; ++j) y += M24[j*TT + t]*tm[j];
  float pos = (y + 1.f)*0.5f*405.f;
  pos = fminf(fmaxf(pos, 0.f), 405.f);
  int i0 = (int)pos;
  float w = pos - (float)i0;
  int i1 = min(i0 + 1, 405);
  const float* p0 = proto + ((size_t)p*TT + i0)*10;
  const float* p1 = proto + ((size_t)p*TT + i1)*10;
  #pragma unroll
  for (int d = 0; d < 10; ++d){
    float val = (p0[d]*(1.f - w) + p1[d]*w + offv[((size_t)b*128 + p)*10 + d])*scv[((size_t)b*128 + p)*10 + d];
    out0[((size_t)b*TT + t)*10 + d] = val;
  }
}

// ---------------- launch ----------------
extern "C" void kernel_launch(void* const* d_in, const int* in_sizes, int n_in,
                              void* d_out, int out_size, void* d_ws, size_t ws_size,
                              hipStream_t stream){
  const float* input_seq = (const float*)d_in[0];
  const int*   label     = (const int*)  d_in[1];
  const int*   mask      = (const int*)  d_in[2];
  const float* proto     = (const float*)d_in[3];
  const float* c1w = (const float*)d_in[4];  const float* c1b = (const float*)d_in[5];
  const float* g1  = (const float*)d_in[6];  const float* b1  = (const float*)d_in[7];
  const float* c2w = (const float*)d_in[8];  const float* c2b = (const float*)d_in[9];
  const float* g2  = (const float*)d_in[10]; const float* b2  = (const float*)d_in[11];
  const float* c3w = (const float*)d_in[12]; const float* c3b = (const float*)d_in[13];
  const float* g3  = (const float*)d_in[14]; const float* b3  = (const float*)d_in[15];
  const float* fw  = (const float*)d_in[16]; const float* fb  = (const float*)d_in[17];
  const float* tw  = (const float*)d_in[18]; const float* tb  = (const float*)d_in[19];
  const float* ow  = (const float*)d_in[20]; const float* ob  = (const float*)d_in[21];
  const float* sw  = (const float*)d_in[22]; const float* sb  = (const float*)d_in[23];

  float* wsf = (float*)d_ws;
  float* out0 = (float*)d_out;             // (B,T,D) 259840
  float* out1 = out0 + 259840;             // inp_s   259840
  float* out2 = out0 + 519680;             // dist    8192
  float* out3 = out0 + 527872;             // indices 64
  float* out4 = out0 + 527936;             // label   64
  float* out5 = out0 + 528000;             // mask_s  25984

  float* h1 = wsf + OFF_H1;
  float* h2 = wsf + OFF_H2;
  float* h3 = h1;                          // h1 dead after conv2
  float* inpT = wsf + OFF_INPT;            // h2 dead after conv3
  unsigned short* wu = (unsigned short*)(wsf + OFF_TMAP);
  const unsigned short* wh2 = wu;
  const unsigned short* wl2 = wu + 163840;
  const unsigned short* wh3 = wu + 327680;
  const unsigned short* wl3 = wu + 327680 + 98304;

  k_tps_inv<<<dim3(1), dim3(256), 0, stream>>>(wsf);
  k_tps_rep<<<dim3(7), dim3(64), 0, stream>>>(wsf);
  k_wprep<<<dim3(1024), dim3(256), 0, stream>>>(c2w, c3w, wu);
  k_conv1<<<dim3(13,BB), 256, 0, stream>>>(input_seq, c1w, c1b, h1);
  k_bnstats<128><<<128, 256, 0, stream>>>(h1, wsf+OFF_MEAN1, wsf+OFF_RSTD1);
  k_conv2m<<<dim3(7,BB), 256, 0, stream>>>(h1, wh2, wl2, c2b, g1, b1, wsf+OFF_MEAN1, wsf+OFF_RSTD1, h2);
  k_bnstats<256><<<256, 256, 0, stream>>>(h2, wsf+OFF_MEAN2, wsf+OFF_RSTD2);
  k_conv3m<<<dim3(7,BB), 256, 0, stream>>>(h2, wh3, wl3, c3b, g2, b2, wsf+OFF_MEAN2, wsf+OFF_RSTD2, h3);
  k_bnstats<128><<<128, 256, 0, stream>>>(h3, wsf+OFF_MEAN3, wsf+OFF_RSTD3);
  k_gap<<<dim3(128,BB), 64, 0, stream>>>(h3, g3, b3, wsf+OFF_MEAN3, wsf+OFF_RSTD3, wsf+OFF_GAP);
  k_feat<<<32, 256, 0, stream>>>(wsf+OFF_GAP, fw, fb, wsf+OFF_FEAT);
  k_trans<<<768, 256, 0, stream>>>(wsf+OFF_FEAT, tw, tb, wsf+OFF_TMAP);
  k_offscale<<<320, 256, 0, stream>>>(wsf+OFF_FEAT, ow, ob, sw, sb, wsf+OFF_OFFV, wsf+OFF_SCV);
  k_smooth<<<dim3(BB,4), 128, 0, stream>>>(input_seq, mask, wsf+OFF_GW, out1, out5, inpT);
  k_dist<<<dim3(128,BB), 64, 0, stream>>>(wsf, proto, inpT, out5, wsf+OFF_OFFV, wsf+OFF_SCV, out2);
  k_argmin<<<1, 64, 0, stream>>>(out2, label, (int*)(wsf+OFF_IDX), out3, out4);
  k_out<<<dim3(7,BB), 64, 0, stream>>>(wsf, proto, wsf+OFF_OFFV, wsf+OFF_SCV, (int*)(wsf+OFF_IDX), out0);
}